// Round 7
// baseline (417.849 us; speedup 1.0000x reference)
//
#include <hip/hip_runtime.h>
#include <math.h>
#include <stdint.h>

#define ND_ROWS 16384
#define DDIM    256
#define KCODES  8192
#define NSEG    128        // 64-code segments
#define NRG     8          // row groups (XCD-affine), 2048 rows each

typedef _Float16 f16x4 __attribute__((ext_vector_type(4)));
typedef _Float16 f16x8 __attribute__((ext_vector_type(8)));
typedef float    f32x4v __attribute__((ext_vector_type(4)));
typedef float    f32x16 __attribute__((ext_vector_type(16)));

// R17: dispatch-fusion round. 6 dispatches -> 3:
//   - minpair/counts init moved into prep (covers both arrays exactly)
//   - scalars fused into finalize via ticket + last-block (body verbatim,
//     so the summation tree and bit-exact loss/perplexity are unchanged)
//   - argmin = exact R14 (best measured: 216 us, 0 bank conflicts, no spill)
// Post-mortem R16: acc[2][4] wide tile hit the 256-reg cap (VGPR 128 + AGPR
// 128) -> C-prefetch spilled (FETCH 218 MB). Every argmin structure lands at
// 40-45% MfmaUtil; register file forbids deeper prefetch. Attack the ~95 us
// of non-argmin time instead.

__device__ unsigned g_ticket;   // reset by prep each call (graph-safe)

// ---------------------------------------------------------------------------
// ws layout (bytes):
//   minpair [0,        131072)   u64[16384]  (init by prep)
//   counts  [131072,   163840)   int[8192]   (init by prep)
//   parts   [163840,   196608)   de[4096] | dq[4096]
//   neF     [196608,   229376)   float[8192] = ||e||^2
//   Xp      [229376,   17006592) x as MFMA B-operand fragments, 16.8 MB
//   Bp      [17006592, 25395200) 8192 x 512 f16 = [-2e_hi(256) | -2e_lo(256)]
// ---------------------------------------------------------------------------

__device__ __attribute__((always_inline)) inline void load_lds16(const void* g, void* l) {
    __builtin_amdgcn_global_load_lds((const __attribute__((address_space(1))) void*)g,
                                     (__attribute__((address_space(3))) void*)l, 16, 0, 0);
}

// one wave per vector. x -> B-operand fragment layout (hi/lo split, unscaled).
// codebook -> row-major [-2e_hi | -2e_lo] (-2 folded in) + float ne table.
// Also zero-inits minpair (x-waves) and counts + ticket (emb-waves).
__global__ __launch_bounds__(256) void prep_kernel(const float* __restrict__ x,
                                                   const float* __restrict__ emb,
                                                   _Float16* __restrict__ Xp,
                                                   _Float16* __restrict__ Bp,
                                                   float* __restrict__ neF,
                                                   unsigned long long* __restrict__ minpair,
                                                   int* __restrict__ counts) {
    int wave = (blockIdx.x << 2) + (threadIdx.x >> 6);   // [0, 24576)
    int lane = threadIdx.x & 63;
    if (wave < ND_ROWS) {
        const float* src = x + (size_t)wave * DDIM;
        float4 v = ((const float4*)src)[lane];           // k = lane*4 .. +4
        f16x4 hi, lo;
        hi[0] = (_Float16)v.x; lo[0] = (_Float16)(v.x - (float)hi[0]);
        hi[1] = (_Float16)v.y; lo[1] = (_Float16)(v.y - (float)hi[1]);
        hi[2] = (_Float16)v.z; lo[2] = (_Float16)(v.z - (float)hi[2]);
        hi[3] = (_Float16)v.w; lo[3] = (_Float16)(v.w - (float)hi[3]);
        int rb = wave >> 5, rl = wave & 31;
        size_t off = (size_t)rb * 16384 + ((lane >> 2) << 9)
                   + (((lane >> 1) & 1) << 8) + (rl << 3) + ((lane & 1) << 2);
        *(f16x4*)(Xp + off)        = hi;
        *(f16x4*)(Xp + off + 8192) = lo;                 // lo block: +16 KB
        if (lane == 0) minpair[wave] = 0xFFFFFFFFFFFFFFFFull;
    } else {
        int r = wave - ND_ROWS;
        const float* src = emb + (size_t)r * DDIM;
        float4 v = ((const float4*)src)[lane];
        float s = v.x*v.x + v.y*v.y + v.z*v.z + v.w*v.w;  // ||e||^2 of original e
        #pragma unroll
        for (int m = 32; m; m >>= 1) s += __shfl_xor(s, m, 64);
        float4 t;                                         // fold the -2 in
        t.x = -2.0f * v.x; t.y = -2.0f * v.y; t.z = -2.0f * v.z; t.w = -2.0f * v.w;
        f16x4 hi, lo;
        hi[0] = (_Float16)t.x; lo[0] = (_Float16)(t.x - (float)hi[0]);
        hi[1] = (_Float16)t.y; lo[1] = (_Float16)(t.y - (float)hi[1]);
        hi[2] = (_Float16)t.z; lo[2] = (_Float16)(t.z - (float)hi[2]);
        hi[3] = (_Float16)t.w; lo[3] = (_Float16)(t.w - (float)hi[3]);
        _Float16* dst = Bp + (size_t)r * 512;
        *(f16x4*)(dst + lane * 4)       = hi;
        *(f16x4*)(dst + 256 + lane * 4) = lo;
        if (lane == 0) {
            neF[r] = s;
            counts[r] = 0;
            if (r == 0) g_ticket = 0u;
        }
    }
}

// Barrier-free argmin GEMM, codes-as-M, mfma_f32_32x32x16_f16, 2-chunk blocked.
// Exact R14 structure (best measured): acc[2][2], unroll 2, launch_bounds
// (512,4), transposed conflict-free code slab, JIT loads, no setprio.
#define MFMA16(A, B, C) __builtin_amdgcn_mfma_f32_32x32x16_f16(A, B, C, 0, 0, 0)

__global__ __launch_bounds__(512, 4) void argmin_seg(
    const _Float16* __restrict__ Xp, const _Float16* __restrict__ Bp,
    const float* __restrict__ neF, unsigned long long* __restrict__ minpair) {
    __shared__ __align__(16) _Float16 Cs[64 * 512];   // 64 KB, nothing else

    const int tid  = threadIdx.x;
    const int lane = tid & 63;
    const int w    = tid >> 6;     // 0..7
    const int c32  = lane & 31;
    const int kg   = lane >> 5;

    const int rg      = blockIdx.x & 7;
    const int seg     = blockIdx.x >> 3;
    const int rowBase = rg * 2048;
    const int code0   = seg * 64;

    // stage code slab TRANSPOSED: LDS chunk j (1 KB, linear dest) holds
    // { slot 2*(j&31)+0 : codes 0..31 | slot 2*(j&31)+1 : codes 0..31 } of
    // code-half (j>>5). Lane l fetches global Bp[code0 + (j&32) + (l&31)]
    // slot (2*(j&31) + (l>>5)).  (16B-gather src; prologue-only, L2-hot.)
    #pragma unroll
    for (int i = 0; i < 8; ++i) {
        int j    = w * 8 + i;
        int code = code0 + (j & 32) + (lane & 31);
        int s    = ((j & 31) << 1) | (lane >> 5);
        load_lds16((const char*)Bp + ((size_t)code << 10) + (s << 4),
                   (char*)Cs + (j << 10));
    }
    __syncthreads();   // the only barrier

    // read base: lane offset c32*16 within a 512B slot-row, kg picks the
    // adjacent slot. Per q: 4 reads at compile-time offsets, each wave-
    // contiguous 1 KB -> conflict-free.
    const char* cpb = (const char*)Cs + (kg << 9) + (c32 << 4);

    const int wBase = rowBase + w * 256;   // 4 chunk-pairs of 64 rows per wave
    for (int c2 = 0; c2 < 4; ++c2) {
        const int rb0 = (wBase >> 5) + c2 * 2;
        const char* xb0 = (const char*)Xp + (size_t)rb0 * 32768 + lane * 16;
        const char* xb1 = xb0 + 32768;
        f32x16 acc[2][2];   // [chunk][mt] - 4 independent MFMA chains, 64 AGPR
        #pragma unroll
        for (int i = 0; i < 16; ++i) {
            acc[0][0][i] = 0.0f; acc[0][1][i] = 0.0f;
            acc[1][0][i] = 0.0f; acc[1][1][i] = 0.0f;
        }

        #pragma unroll 2
        for (int q = 0; q < 16; ++q) {
            f16x8 xh0 = *(const f16x8*)(xb0 + q * 1024);
            f16x8 xl0 = *(const f16x8*)(xb0 + 16384 + q * 1024);
            f16x8 xh1 = *(const f16x8*)(xb1 + q * 1024);
            f16x8 xl1 = *(const f16x8*)(xb1 + 16384 + q * 1024);
            f16x8 ch0 = *(const f16x8*)(cpb + q * 1024);
            f16x8 cl0 = *(const f16x8*)(cpb + 16384 + q * 1024);
            f16x8 ch1 = *(const f16x8*)(cpb + 32768 + q * 1024);
            f16x8 cl1 = *(const f16x8*)(cpb + 49152 + q * 1024);
            // 12 MFMAs, chain-interleaved (each chain's next issue is 4 slots away)
            acc[0][0] = MFMA16(ch0, xh0, acc[0][0]);
            acc[0][1] = MFMA16(ch1, xh0, acc[0][1]);
            acc[1][0] = MFMA16(ch0, xh1, acc[1][0]);
            acc[1][1] = MFMA16(ch1, xh1, acc[1][1]);
            acc[0][0] = MFMA16(ch0, xl0, acc[0][0]);
            acc[0][1] = MFMA16(ch1, xl0, acc[0][1]);
            acc[1][0] = MFMA16(ch0, xl1, acc[1][0]);
            acc[1][1] = MFMA16(ch1, xl1, acc[1][1]);
            acc[0][0] = MFMA16(cl0, xh0, acc[0][0]);
            acc[0][1] = MFMA16(cl1, xh0, acc[0][1]);
            acc[1][0] = MFMA16(cl0, xh1, acc[1][0]);
            acc[1][1] = MFMA16(cl1, xh1, acc[1][1]);
        }

        // epilogue: ne loaded here only (L1-hot after first iter). Code id of
        // acc[ck][mt][r] = code0 + mt*32 + 4*kg + (r&3) + 8*(r>>2); (mt,r)
        // ascending <=> id ascending; strict < => first(lowest-index)-wins.
        f32x4v ne4[2][4];
        #pragma unroll
        for (int mt = 0; mt < 2; ++mt)
            #pragma unroll
            for (int g2 = 0; g2 < 4; ++g2)
                ne4[mt][g2] = *(const f32x4v*)(neF + code0 + mt * 32 + g2 * 8 + 4 * kg);
        #pragma unroll
        for (int ck = 0; ck < 2; ++ck) {
            float best = 3.402823466e+38f;
            int   bi   = 0;
            #pragma unroll
            for (int mt = 0; mt < 2; ++mt)
                #pragma unroll
                for (int r = 0; r < 16; ++r) {
                    float d  = acc[ck][mt][r] + ne4[mt][r >> 2][r & 3];
                    int   id = code0 + mt * 32 + 4 * kg + ((r & 3) + 8 * (r >> 2));
                    if (d < best) { best = d; bi = id; }
                }
            float ov = __shfl_xor(best, 32, 64);
            int   oi = __shfl_xor(bi, 32, 64);
            if (ov < best || (ov == best && oi < bi)) { best = ov; bi = oi; }
            if (kg == 0) {
                int row = (rb0 + ck) * 32 + c32;
                unsigned u = __float_as_uint(best);
                u = (u & 0x80000000u) ? ~u : (u | 0x80000000u);   // total-order map
                atomicMin(&minpair[row],
                          (((unsigned long long)u) << 32) | (unsigned)bi);
            }
        }
    }
}

// decode packed min, gather codebook row, write quantized_sg + float index,
// histogram atomic + per-block SSE partials. LAST block (ticket) then runs
// the scalars reduction (body verbatim from the old scalars_kernel -> same
// summation tree -> bit-identical loss/perplexity).
__global__ __launch_bounds__(256) void finalize_kernel(
    const float* __restrict__ x, const float* __restrict__ emb,
    const unsigned long long* __restrict__ minpair,
    float* __restrict__ out_q, float* __restrict__ out_idx,
    int* __restrict__ counts, float* __restrict__ parts,
    float* __restrict__ out_loss, float* __restrict__ out_perp) {
    __shared__ float rde[4], rdq[4];
    __shared__ unsigned is_last;
    int wv   = threadIdx.x >> 6;
    int row  = (blockIdx.x << 2) + wv;
    int lane = threadIdx.x & 63;

    int bi = (int)(minpair[row] & 0xFFFFFFFFull);

    float4 xv = ((const float4*)(x   + (size_t)row * DDIM))[lane];
    float4 ev = ((const float4*)(emb + (size_t)bi  * DDIM))[lane];
    float4 q;
    q.x = xv.x + (ev.x - xv.x);
    q.y = xv.y + (ev.y - xv.y);
    q.z = xv.z + (ev.z - xv.z);
    q.w = xv.w + (ev.w - xv.w);
    ((float4*)(out_q + (size_t)row * DDIM))[lane] = q;

    float de = (ev.x - xv.x) * (ev.x - xv.x) + (ev.y - xv.y) * (ev.y - xv.y)
             + (ev.z - xv.z) * (ev.z - xv.z) + (ev.w - xv.w) * (ev.w - xv.w);
    float dq = (q.x - ev.x) * (q.x - ev.x) + (q.y - ev.y) * (q.y - ev.y)
             + (q.z - ev.z) * (q.z - ev.z) + (q.w - ev.w) * (q.w - ev.w);
    #pragma unroll
    for (int m = 32; m; m >>= 1) {
        de += __shfl_xor(de, m, 64);
        dq += __shfl_xor(dq, m, 64);
    }
    if (lane == 0) {
        out_idx[row] = (float)bi;
        atomicAdd(&counts[bi], 1);
        rde[wv] = de; rdq[wv] = dq;
    }
    __syncthreads();
    if (threadIdx.x == 0) {
        parts[blockIdx.x]        = rde[0] + rde[1] + rde[2] + rde[3];
        parts[4096 + blockIdx.x] = rdq[0] + rdq[1] + rdq[2] + rdq[3];
        __threadfence();
        unsigned t = atomicAdd(&g_ticket, 1u);
        is_last = (t == (unsigned)(gridDim.x - 1)) ? 1u : 0u;
    }
    __syncthreads();

    if (is_last) {
        __threadfence();   // acquire: see all blocks' parts/counts
        __shared__ float red[256], rde2[256], rdq2[256];
        float local = 0.0f, de2 = 0.0f, dq2 = 0.0f;
        for (int k = threadIdx.x; k < KCODES; k += 256) {
            float p = (float)counts[k] * (1.0f / (float)ND_ROWS);
            local += p * logf(p + 1e-10f);
        }
        for (int k = threadIdx.x; k < 4096; k += 256) {
            de2 += parts[k];
            dq2 += parts[4096 + k];
        }
        red[threadIdx.x] = local; rde2[threadIdx.x] = de2; rdq2[threadIdx.x] = dq2;
        __syncthreads();
        for (int s = 128; s; s >>= 1) {
            if (threadIdx.x < s) {
                red[threadIdx.x]  += red[threadIdx.x + s];
                rde2[threadIdx.x] += rde2[threadIdx.x + s];
                rdq2[threadIdx.x] += rdq2[threadIdx.x + s];
            }
            __syncthreads();
        }
        if (threadIdx.x == 0) {
            *out_perp = expf(-red[0]);
            float invn = 1.0f / (float)(ND_ROWS * DDIM);
            *out_loss = rdq2[0] * invn + 0.25f * (rde2[0] * invn);
        }
    }
}

extern "C" void kernel_launch(void* const* d_in, const int* in_sizes, int n_in,
                              void* d_out, int out_size, void* d_ws, size_t ws_size,
                              hipStream_t stream) {
    const float* x   = (const float*)d_in[0];
    const float* emb = (const float*)d_in[1];

    char* ws = (char*)d_ws;
    unsigned long long* minpair = (unsigned long long*)ws;         // 128 KB
    int*      counts = (int*)(ws + 131072);                        // 32 KB
    float*    parts  = (float*)(ws + 163840);                      // 32 KB
    float*    neF    = (float*)(ws + 196608);                      // 32 KB
    _Float16* Xp     = (_Float16*)(ws + 229376);                   // 16.8 MB
    _Float16* Bp     = (_Float16*)(ws + 17006592);                 // 8.4 MB

    float* out_q    = (float*)d_out;
    float* out_idx  = out_q + (size_t)ND_ROWS * DDIM;
    float* out_loss = out_idx + ND_ROWS;
    float* out_perp = out_loss + 1;

    prep_kernel<<<(KCODES + ND_ROWS) / 4, 256, 0, stream>>>(x, emb, Xp, Bp, neF,
                                                            minpair, counts);
    argmin_seg<<<NRG * NSEG, 512, 0, stream>>>(Xp, Bp, neF, minpair);
    finalize_kernel<<<ND_ROWS / 4, 256, 0, stream>>>(x, emb, minpair,
                                                     out_q, out_idx, counts, parts,
                                                     out_loss, out_perp);
}

// Round 8
// 324.957 us; speedup vs baseline: 1.2859x; 1.2859x over previous
//
#include <hip/hip_runtime.h>
#include <math.h>
#include <stdint.h>

#define ND_ROWS 16384
#define DDIM    256
#define KCODES  8192
#define NSEG    128        // 64-code segments
#define NRG     8          // row groups (XCD-affine), 2048 rows each

typedef _Float16 f16x4 __attribute__((ext_vector_type(4)));
typedef _Float16 f16x8 __attribute__((ext_vector_type(8)));
typedef float    f32x4v __attribute__((ext_vector_type(4)));
typedef float    f32x16 __attribute__((ext_vector_type(16)));

// R18:
//  - finalize/scalars fusion REVERTED (R17 post-mortem: 4096 per-block
//    __threadfence()s on non-coherent XCD L2s doubled non-argmin time,
//    94 -> 206 us). Separate scalars dispatch restored.
//  - memset-free init kept (prep covers minpair + counts exactly).
//  - argmin: X-only register double-buffer under the 128-reg quantum.
//    Register model (validated R14/R15): R14 = 64V+64A = 128 -> 4 waves/SIMD,
//    duty 11%; R15 = 116V+64A = 180 -> 2 waves/SIMD, duty 22% (pipeline
//    works, occupancy cancels it). Win condition: pipelined wave <= 128 regs.
//    X (L2, ~200-300 cyc) is the exposed latency -> 2-stage reg dbuf (32 V);
//    C (LDS, ~120 cyc, hideable at 4 waves) stays JIT (16 V). ~58-64 V + 64 A.
// ---------------------------------------------------------------------------
// ws layout (bytes):
//   minpair [0,        131072)   u64[16384]  (init by prep)
//   counts  [131072,   163840)   int[8192]   (init by prep)
//   parts   [163840,   196608)   de[4096] | dq[4096]
//   neF     [196608,   229376)   float[8192] = ||e||^2
//   Xp      [229376,   17006592) x as MFMA B-operand fragments, 16.8 MB
//   Bp      [17006592, 25395200) 8192 x 512 f16 = [-2e_hi(256) | -2e_lo(256)]
// ---------------------------------------------------------------------------

__device__ __attribute__((always_inline)) inline void load_lds16(const void* g, void* l) {
    __builtin_amdgcn_global_load_lds((const __attribute__((address_space(1))) void*)g,
                                     (__attribute__((address_space(3))) void*)l, 16, 0, 0);
}

// one wave per vector. x -> B-operand fragment layout (hi/lo split, unscaled).
// codebook -> row-major [-2e_hi | -2e_lo] (-2 folded in) + float ne table.
// Also inits minpair (x-waves) and counts (emb-waves) - replaces 2 memsets.
__global__ __launch_bounds__(256) void prep_kernel(const float* __restrict__ x,
                                                   const float* __restrict__ emb,
                                                   _Float16* __restrict__ Xp,
                                                   _Float16* __restrict__ Bp,
                                                   float* __restrict__ neF,
                                                   unsigned long long* __restrict__ minpair,
                                                   int* __restrict__ counts) {
    int wave = (blockIdx.x << 2) + (threadIdx.x >> 6);   // [0, 24576)
    int lane = threadIdx.x & 63;
    if (wave < ND_ROWS) {
        const float* src = x + (size_t)wave * DDIM;
        float4 v = ((const float4*)src)[lane];           // k = lane*4 .. +4
        f16x4 hi, lo;
        hi[0] = (_Float16)v.x; lo[0] = (_Float16)(v.x - (float)hi[0]);
        hi[1] = (_Float16)v.y; lo[1] = (_Float16)(v.y - (float)hi[1]);
        hi[2] = (_Float16)v.z; lo[2] = (_Float16)(v.z - (float)hi[2]);
        hi[3] = (_Float16)v.w; lo[3] = (_Float16)(v.w - (float)hi[3]);
        int rb = wave >> 5, rl = wave & 31;
        size_t off = (size_t)rb * 16384 + ((lane >> 2) << 9)
                   + (((lane >> 1) & 1) << 8) + (rl << 3) + ((lane & 1) << 2);
        *(f16x4*)(Xp + off)        = hi;
        *(f16x4*)(Xp + off + 8192) = lo;                 // lo block: +16 KB
        if (lane == 0) minpair[wave] = 0xFFFFFFFFFFFFFFFFull;
    } else {
        int r = wave - ND_ROWS;
        const float* src = emb + (size_t)r * DDIM;
        float4 v = ((const float4*)src)[lane];
        float s = v.x*v.x + v.y*v.y + v.z*v.z + v.w*v.w;  // ||e||^2 of original e
        #pragma unroll
        for (int m = 32; m; m >>= 1) s += __shfl_xor(s, m, 64);
        float4 t;                                         // fold the -2 in
        t.x = -2.0f * v.x; t.y = -2.0f * v.y; t.z = -2.0f * v.z; t.w = -2.0f * v.w;
        f16x4 hi, lo;
        hi[0] = (_Float16)t.x; lo[0] = (_Float16)(t.x - (float)hi[0]);
        hi[1] = (_Float16)t.y; lo[1] = (_Float16)(t.y - (float)hi[1]);
        hi[2] = (_Float16)t.z; lo[2] = (_Float16)(t.z - (float)hi[2]);
        hi[3] = (_Float16)t.w; lo[3] = (_Float16)(t.w - (float)hi[3]);
        _Float16* dst = Bp + (size_t)r * 512;
        *(f16x4*)(dst + lane * 4)       = hi;
        *(f16x4*)(dst + 256 + lane * 4) = lo;
        if (lane == 0) {
            neF[r] = s;
            counts[r] = 0;
        }
    }
}

// Barrier-free argmin GEMM, codes-as-M, mfma_f32_32x32x16_f16, 2-chunk blocked.
// R18 structure: R14 (acc[2][2], transposed conflict-free slab, 512x4) +
// X-only 2-stage register double-buffer, hard unroll 1, C JIT from LDS.
#define MFMA16(A, B, C) __builtin_amdgcn_mfma_f32_32x32x16_f16(A, B, C, 0, 0, 0)

// X stage: P0=xh0, P1=xl0, P2=xh1, P3=xl1 (chunk 0/1, hi/lo).
#define LOADXS(P, qq) { \
    P##0 = *(const f16x8*)(xb0 + (qq) * 1024); \
    P##1 = *(const f16x8*)(xb0 + 16384 + (qq) * 1024); \
    P##2 = *(const f16x8*)(xb1 + (qq) * 1024); \
    P##3 = *(const f16x8*)(xb1 + 16384 + (qq) * 1024); }

// 12 MFMAs for stage P against C frags of step qq (JIT ds_reads).
// 4 chains round-robin (spacing 4 slots). Products: ch*xh + ch*xl + cl*xh.
#define HALF(P, qq) { \
    f16x8 ch0 = *(const f16x8*)(cpb + (qq) * 1024); \
    f16x8 cl0 = *(const f16x8*)(cpb + 16384 + (qq) * 1024); \
    f16x8 ch1 = *(const f16x8*)(cpb + 32768 + (qq) * 1024); \
    f16x8 cl1 = *(const f16x8*)(cpb + 49152 + (qq) * 1024); \
    acc[0][0] = MFMA16(ch0, P##0, acc[0][0]); \
    acc[0][1] = MFMA16(ch1, P##0, acc[0][1]); \
    acc[1][0] = MFMA16(ch0, P##2, acc[1][0]); \
    acc[1][1] = MFMA16(ch1, P##2, acc[1][1]); \
    acc[0][0] = MFMA16(ch0, P##1, acc[0][0]); \
    acc[0][1] = MFMA16(ch1, P##1, acc[0][1]); \
    acc[1][0] = MFMA16(ch0, P##3, acc[1][0]); \
    acc[1][1] = MFMA16(ch1, P##3, acc[1][1]); \
    acc[0][0] = MFMA16(cl0, P##0, acc[0][0]); \
    acc[0][1] = MFMA16(cl1, P##0, acc[0][1]); \
    acc[1][0] = MFMA16(cl0, P##2, acc[1][0]); \
    acc[1][1] = MFMA16(cl1, P##2, acc[1][1]); }

__global__ __launch_bounds__(512, 4) void argmin_seg(
    const _Float16* __restrict__ Xp, const _Float16* __restrict__ Bp,
    const float* __restrict__ neF, unsigned long long* __restrict__ minpair) {
    __shared__ __align__(16) _Float16 Cs[64 * 512];   // 64 KB, nothing else

    const int tid  = threadIdx.x;
    const int lane = tid & 63;
    const int w    = tid >> 6;     // 0..7
    const int c32  = lane & 31;
    const int kg   = lane >> 5;

    const int rg      = blockIdx.x & 7;
    const int seg     = blockIdx.x >> 3;
    const int rowBase = rg * 2048;
    const int code0   = seg * 64;

    // stage code slab TRANSPOSED: LDS chunk j (1 KB, linear dest) holds
    // { slot 2*(j&31)+0 : codes 0..31 | slot 2*(j&31)+1 : codes 0..31 } of
    // code-half (j>>5). Lane l fetches global Bp[code0 + (j&32) + (l&31)]
    // slot (2*(j&31) + (l>>5)).  (16B-gather src; prologue-only, L2-hot.)
    #pragma unroll
    for (int i = 0; i < 8; ++i) {
        int j    = w * 8 + i;
        int code = code0 + (j & 32) + (lane & 31);
        int s    = ((j & 31) << 1) | (lane >> 5);
        load_lds16((const char*)Bp + ((size_t)code << 10) + (s << 4),
                   (char*)Cs + (j << 10));
    }
    __syncthreads();   // the only barrier

    // read base: lane offset c32*16 within a 512B slot-row, kg picks the
    // adjacent slot. Per q: 4 reads at compile-time offsets, each wave-
    // contiguous 1 KB -> conflict-free.
    const char* cpb = (const char*)Cs + (kg << 9) + (c32 << 4);

    const int wBase = rowBase + w * 256;   // 4 chunk-pairs of 64 rows per wave
    #pragma unroll 1
    for (int c2 = 0; c2 < 4; ++c2) {
        const int rb0 = (wBase >> 5) + c2 * 2;
        const char* xb0 = (const char*)Xp + (size_t)rb0 * 32768 + lane * 16;
        const char* xb1 = xb0 + 32768;
        f32x16 acc[2][2];   // [chunk][mt] - 4 independent MFMA chains, 64 AGPR
        #pragma unroll
        for (int i = 0; i < 16; ++i) {
            acc[0][0][i] = 0.0f; acc[0][1][i] = 0.0f;
            acc[1][0][i] = 0.0f; acc[1][1][i] = 0.0f;
        }

        f16x8 sa0, sa1, sa2, sa3;   // X stage A
        f16x8 sb0, sb1, sb2, sb3;   // X stage B
        LOADXS(sa, 0)
        #pragma unroll 1
        for (int q = 0; q < 16; q += 2) {
            LOADXS(sb, q + 1)            // prefetch next X a full half ahead
            HALF(sa, q)
            LOADXS(sa, (q + 2) & 15)     // wrap: 1 redundant L2-hit prefetch
            HALF(sb, q + 1)
        }

        // epilogue: ne loaded here only (L1-hot after first iter). Code id of
        // acc[ck][mt][r] = code0 + mt*32 + 4*kg + (r&3) + 8*(r>>2); (mt,r)
        // ascending <=> id ascending; strict < => first(lowest-index)-wins.
        f32x4v ne4[2][4];
        #pragma unroll
        for (int mt = 0; mt < 2; ++mt)
            #pragma unroll
            for (int g2 = 0; g2 < 4; ++g2)
                ne4[mt][g2] = *(const f32x4v*)(neF + code0 + mt * 32 + g2 * 8 + 4 * kg);
        #pragma unroll
        for (int ck = 0; ck < 2; ++ck) {
            float best = 3.402823466e+38f;
            int   bi   = 0;
            #pragma unroll
            for (int mt = 0; mt < 2; ++mt)
                #pragma unroll
                for (int r = 0; r < 16; ++r) {
                    float d  = acc[ck][mt][r] + ne4[mt][r >> 2][r & 3];
                    int   id = code0 + mt * 32 + 4 * kg + ((r & 3) + 8 * (r >> 2));
                    if (d < best) { best = d; bi = id; }
                }
            float ov = __shfl_xor(best, 32, 64);
            int   oi = __shfl_xor(bi, 32, 64);
            if (ov < best || (ov == best && oi < bi)) { best = ov; bi = oi; }
            if (kg == 0) {
                int row = (rb0 + ck) * 32 + c32;
                unsigned u = __float_as_uint(best);
                u = (u & 0x80000000u) ? ~u : (u | 0x80000000u);   // total-order map
                atomicMin(&minpair[row],
                          (((unsigned long long)u) << 32) | (unsigned)bi);
            }
        }
    }
}

// decode packed min, gather codebook row, write quantized_sg + float index,
// histogram atomic + per-block SSE partials.
__global__ __launch_bounds__(256) void finalize_kernel(
    const float* __restrict__ x, const float* __restrict__ emb,
    const unsigned long long* __restrict__ minpair,
    float* __restrict__ out_q, float* __restrict__ out_idx,
    int* __restrict__ counts, float* __restrict__ parts) {
    __shared__ float rde[4], rdq[4];
    int wv   = threadIdx.x >> 6;
    int row  = (blockIdx.x << 2) + wv;
    int lane = threadIdx.x & 63;

    int bi = (int)(minpair[row] & 0xFFFFFFFFull);

    float4 xv = ((const float4*)(x   + (size_t)row * DDIM))[lane];
    float4 ev = ((const float4*)(emb + (size_t)bi  * DDIM))[lane];
    float4 q;
    q.x = xv.x + (ev.x - xv.x);
    q.y = xv.y + (ev.y - xv.y);
    q.z = xv.z + (ev.z - xv.z);
    q.w = xv.w + (ev.w - xv.w);
    ((float4*)(out_q + (size_t)row * DDIM))[lane] = q;

    float de = (ev.x - xv.x) * (ev.x - xv.x) + (ev.y - xv.y) * (ev.y - xv.y)
             + (ev.z - xv.z) * (ev.z - xv.z) + (ev.w - xv.w) * (ev.w - xv.w);
    float dq = (q.x - ev.x) * (q.x - ev.x) + (q.y - ev.y) * (q.y - ev.y)
             + (q.z - ev.z) * (q.z - ev.z) + (q.w - ev.w) * (q.w - ev.w);
    #pragma unroll
    for (int m = 32; m; m >>= 1) {
        de += __shfl_xor(de, m, 64);
        dq += __shfl_xor(dq, m, 64);
    }
    if (lane == 0) {
        out_idx[row] = (float)bi;
        atomicAdd(&counts[bi], 1);
        rde[wv] = de; rdq[wv] = dq;
    }
    __syncthreads();
    if (threadIdx.x == 0) {
        parts[blockIdx.x]        = rde[0] + rde[1] + rde[2] + rde[3];
        parts[4096 + blockIdx.x] = rdq[0] + rdq[1] + rdq[2] + rdq[3];
    }
}

__global__ __launch_bounds__(256) void scalars_kernel(
    const int* __restrict__ counts, const float* __restrict__ parts,
    float* __restrict__ out_loss, float* __restrict__ out_perp) {
    __shared__ float red[256], rde[256], rdq[256];
    float local = 0.0f, de = 0.0f, dq = 0.0f;
    for (int k = threadIdx.x; k < KCODES; k += 256) {
        float p = (float)counts[k] * (1.0f / (float)ND_ROWS);
        local += p * logf(p + 1e-10f);
    }
    for (int k = threadIdx.x; k < 4096; k += 256) {
        de += parts[k];
        dq += parts[4096 + k];
    }
    red[threadIdx.x] = local; rde[threadIdx.x] = de; rdq[threadIdx.x] = dq;
    __syncthreads();
    for (int s = 128; s; s >>= 1) {
        if (threadIdx.x < s) {
            red[threadIdx.x] += red[threadIdx.x + s];
            rde[threadIdx.x] += rde[threadIdx.x + s];
            rdq[threadIdx.x] += rdq[threadIdx.x + s];
        }
        __syncthreads();
    }
    if (threadIdx.x == 0) {
        *out_perp = expf(-red[0]);
        float invn = 1.0f / (float)(ND_ROWS * DDIM);
        *out_loss = rdq[0] * invn + 0.25f * (rde[0] * invn);
    }
}

extern "C" void kernel_launch(void* const* d_in, const int* in_sizes, int n_in,
                              void* d_out, int out_size, void* d_ws, size_t ws_size,
                              hipStream_t stream) {
    const float* x   = (const float*)d_in[0];
    const float* emb = (const float*)d_in[1];

    char* ws = (char*)d_ws;
    unsigned long long* minpair = (unsigned long long*)ws;         // 128 KB
    int*      counts = (int*)(ws + 131072);                        // 32 KB
    float*    parts  = (float*)(ws + 163840);                      // 32 KB
    float*    neF    = (float*)(ws + 196608);                      // 32 KB
    _Float16* Xp     = (_Float16*)(ws + 229376);                   // 16.8 MB
    _Float16* Bp     = (_Float16*)(ws + 17006592);                 // 8.4 MB

    float* out_q    = (float*)d_out;
    float* out_idx  = out_q + (size_t)ND_ROWS * DDIM;
    float* out_loss = out_idx + ND_ROWS;
    float* out_perp = out_loss + 1;

    prep_kernel<<<(KCODES + ND_ROWS) / 4, 256, 0, stream>>>(x, emb, Xp, Bp, neF,
                                                            minpair, counts);
    argmin_seg<<<NRG * NSEG, 512, 0, stream>>>(Xp, Bp, neF, minpair);
    finalize_kernel<<<ND_ROWS / 4, 256, 0, stream>>>(x, emb, minpair,
                                                     out_q, out_idx, counts, parts);
    scalars_kernel<<<1, 256, 0, stream>>>(counts, parts, out_loss, out_perp);
}

// Round 9
// 320.334 us; speedup vs baseline: 1.3044x; 1.0144x over previous
//
#include <hip/hip_runtime.h>
#include <math.h>
#include <stdint.h>

#define ND_ROWS 16384
#define DDIM    256
#define KCODES  8192
#define NSEG    128        // 64-code segments
#define NRG     8          // row groups (XCD-affine), 2048 rows each

typedef _Float16 f16x4 __attribute__((ext_vector_type(4)));
typedef _Float16 f16x8 __attribute__((ext_vector_type(8)));
typedef float    f32x4v __attribute__((ext_vector_type(4)));
typedef float    f32x16 __attribute__((ext_vector_type(16)));

// R19: R18's X-only register double-buffer, spill eliminated.
// Post-mortem R18: VGPR=64 + Occ 40% (4 waves/SIMD, pipeline in place) but
// FETCH 233/WRITE 114 MB scratch traffic: compiler hoisted the epilogue
// ne4[2][4] loads (32 VGPR) above the q-loop -> demand ~90 > 64 cap -> spill.
// Fixes: (1) sched_barrier(0) fences epilogue loads out of the loop;
// (2) peeled tail instead of (q+2)&15 wrap; (3) HALF split into ch-phase
// (8 MFMA) + cl-phase (4 MFMA): C liveness 16->8 VGPR. Demand ~52-55 < 64.
// ---------------------------------------------------------------------------
// ws layout (bytes):
//   minpair [0,        131072)   u64[16384]  (init by prep)
//   counts  [131072,   163840)   int[8192]   (init by prep)
//   parts   [163840,   196608)   de[4096] | dq[4096]
//   neF     [196608,   229376)   float[8192] = ||e||^2
//   Xp      [229376,   17006592) x as MFMA B-operand fragments, 16.8 MB
//   Bp      [17006592, 25395200) 8192 x 512 f16 = [-2e_hi(256) | -2e_lo(256)]
// ---------------------------------------------------------------------------

__device__ __attribute__((always_inline)) inline void load_lds16(const void* g, void* l) {
    __builtin_amdgcn_global_load_lds((const __attribute__((address_space(1))) void*)g,
                                     (__attribute__((address_space(3))) void*)l, 16, 0, 0);
}

// one wave per vector. x -> B-operand fragment layout (hi/lo split, unscaled).
// codebook -> row-major [-2e_hi | -2e_lo] (-2 folded in) + float ne table.
// Also inits minpair (x-waves) and counts (emb-waves) - replaces 2 memsets.
__global__ __launch_bounds__(256) void prep_kernel(const float* __restrict__ x,
                                                   const float* __restrict__ emb,
                                                   _Float16* __restrict__ Xp,
                                                   _Float16* __restrict__ Bp,
                                                   float* __restrict__ neF,
                                                   unsigned long long* __restrict__ minpair,
                                                   int* __restrict__ counts) {
    int wave = (blockIdx.x << 2) + (threadIdx.x >> 6);   // [0, 24576)
    int lane = threadIdx.x & 63;
    if (wave < ND_ROWS) {
        const float* src = x + (size_t)wave * DDIM;
        float4 v = ((const float4*)src)[lane];           // k = lane*4 .. +4
        f16x4 hi, lo;
        hi[0] = (_Float16)v.x; lo[0] = (_Float16)(v.x - (float)hi[0]);
        hi[1] = (_Float16)v.y; lo[1] = (_Float16)(v.y - (float)hi[1]);
        hi[2] = (_Float16)v.z; lo[2] = (_Float16)(v.z - (float)hi[2]);
        hi[3] = (_Float16)v.w; lo[3] = (_Float16)(v.w - (float)hi[3]);
        int rb = wave >> 5, rl = wave & 31;
        size_t off = (size_t)rb * 16384 + ((lane >> 2) << 9)
                   + (((lane >> 1) & 1) << 8) + (rl << 3) + ((lane & 1) << 2);
        *(f16x4*)(Xp + off)        = hi;
        *(f16x4*)(Xp + off + 8192) = lo;                 // lo block: +16 KB
        if (lane == 0) minpair[wave] = 0xFFFFFFFFFFFFFFFFull;
    } else {
        int r = wave - ND_ROWS;
        const float* src = emb + (size_t)r * DDIM;
        float4 v = ((const float4*)src)[lane];
        float s = v.x*v.x + v.y*v.y + v.z*v.z + v.w*v.w;  // ||e||^2 of original e
        #pragma unroll
        for (int m = 32; m; m >>= 1) s += __shfl_xor(s, m, 64);
        float4 t;                                         // fold the -2 in
        t.x = -2.0f * v.x; t.y = -2.0f * v.y; t.z = -2.0f * v.z; t.w = -2.0f * v.w;
        f16x4 hi, lo;
        hi[0] = (_Float16)t.x; lo[0] = (_Float16)(t.x - (float)hi[0]);
        hi[1] = (_Float16)t.y; lo[1] = (_Float16)(t.y - (float)hi[1]);
        hi[2] = (_Float16)t.z; lo[2] = (_Float16)(t.z - (float)hi[2]);
        hi[3] = (_Float16)t.w; lo[3] = (_Float16)(t.w - (float)hi[3]);
        _Float16* dst = Bp + (size_t)r * 512;
        *(f16x4*)(dst + lane * 4)       = hi;
        *(f16x4*)(dst + 256 + lane * 4) = lo;
        if (lane == 0) {
            neF[r] = s;
            counts[r] = 0;
        }
    }
}

// Barrier-free argmin GEMM, codes-as-M, mfma_f32_32x32x16_f16, 2-chunk blocked.
// R19 structure: R14 slab + X-only 2-stage reg dbuf, peeled tail, split-C
// HALF, sched_barrier anti-hoist. Hard unroll 1.
#define MFMA16(A, B, C) __builtin_amdgcn_mfma_f32_32x32x16_f16(A, B, C, 0, 0, 0)

// X stage: P0=xh0, P1=xl0, P2=xh1, P3=xl1 (chunk 0/1, hi/lo).
#define LOADXS(P, qq) { \
    P##0 = *(const f16x8*)(xb0 + (qq) * 1024); \
    P##1 = *(const f16x8*)(xb0 + 16384 + (qq) * 1024); \
    P##2 = *(const f16x8*)(xb1 + (qq) * 1024); \
    P##3 = *(const f16x8*)(xb1 + 16384 + (qq) * 1024); }

// 12 MFMAs for stage P against C frags of step qq, C split into two phases
// (ch pair live for 8 MFMAs, then cl pair for 4): C liveness 8 VGPR.
// 4 chains round-robin (spacing 4 slots). Products: ch*xh + ch*xl + cl*xh.
#define HALF(P, qq) { \
    f16x8 ch0 = *(const f16x8*)(cpb + (qq) * 1024); \
    f16x8 ch1 = *(const f16x8*)(cpb + 32768 + (qq) * 1024); \
    acc[0][0] = MFMA16(ch0, P##0, acc[0][0]); \
    acc[0][1] = MFMA16(ch1, P##0, acc[0][1]); \
    acc[1][0] = MFMA16(ch0, P##2, acc[1][0]); \
    acc[1][1] = MFMA16(ch1, P##2, acc[1][1]); \
    acc[0][0] = MFMA16(ch0, P##1, acc[0][0]); \
    acc[0][1] = MFMA16(ch1, P##1, acc[0][1]); \
    acc[1][0] = MFMA16(ch0, P##3, acc[1][0]); \
    acc[1][1] = MFMA16(ch1, P##3, acc[1][1]); \
    f16x8 cl0 = *(const f16x8*)(cpb + 16384 + (qq) * 1024); \
    f16x8 cl1 = *(const f16x8*)(cpb + 49152 + (qq) * 1024); \
    acc[0][0] = MFMA16(cl0, P##0, acc[0][0]); \
    acc[0][1] = MFMA16(cl1, P##0, acc[0][1]); \
    acc[1][0] = MFMA16(cl0, P##2, acc[1][0]); \
    acc[1][1] = MFMA16(cl1, P##2, acc[1][1]); }

__global__ __launch_bounds__(512, 4) void argmin_seg(
    const _Float16* __restrict__ Xp, const _Float16* __restrict__ Bp,
    const float* __restrict__ neF, unsigned long long* __restrict__ minpair) {
    __shared__ __align__(16) _Float16 Cs[64 * 512];   // 64 KB, nothing else

    const int tid  = threadIdx.x;
    const int lane = tid & 63;
    const int w    = tid >> 6;     // 0..7
    const int c32  = lane & 31;
    const int kg   = lane >> 5;

    const int rg      = blockIdx.x & 7;
    const int seg     = blockIdx.x >> 3;
    const int rowBase = rg * 2048;
    const int code0   = seg * 64;

    // stage code slab TRANSPOSED: LDS chunk j (1 KB, linear dest) holds
    // { slot 2*(j&31)+0 : codes 0..31 | slot 2*(j&31)+1 : codes 0..31 } of
    // code-half (j>>5). Lane l fetches global Bp[code0 + (j&32) + (l&31)]
    // slot (2*(j&31) + (l>>5)).  (16B-gather src; prologue-only, L2-hot.)
    #pragma unroll
    for (int i = 0; i < 8; ++i) {
        int j    = w * 8 + i;
        int code = code0 + (j & 32) + (lane & 31);
        int s    = ((j & 31) << 1) | (lane >> 5);
        load_lds16((const char*)Bp + ((size_t)code << 10) + (s << 4),
                   (char*)Cs + (j << 10));
    }
    __syncthreads();   // the only barrier

    // read base: lane offset c32*16 within a 512B slot-row, kg picks the
    // adjacent slot. Per q: 4 reads at compile-time offsets, each wave-
    // contiguous 1 KB -> conflict-free.
    const char* cpb = (const char*)Cs + (kg << 9) + (c32 << 4);

    const int wBase = rowBase + w * 256;   // 4 chunk-pairs of 64 rows per wave
    #pragma unroll 1
    for (int c2 = 0; c2 < 4; ++c2) {
        const int rb0 = (wBase >> 5) + c2 * 2;
        const char* xb0 = (const char*)Xp + (size_t)rb0 * 32768 + lane * 16;
        const char* xb1 = xb0 + 32768;
        f32x16 acc[2][2];   // [chunk][mt] - 4 independent MFMA chains, 64 AGPR
        #pragma unroll
        for (int i = 0; i < 16; ++i) {
            acc[0][0][i] = 0.0f; acc[0][1][i] = 0.0f;
            acc[1][0][i] = 0.0f; acc[1][1][i] = 0.0f;
        }

        f16x8 sa0, sa1, sa2, sa3;   // X stage A
        f16x8 sb0, sb1, sb2, sb3;   // X stage B
        LOADXS(sa, 0)
        #pragma unroll 1
        for (int q = 0; q < 14; q += 2) {
            LOADXS(sb, q + 1)            // prefetch next X a full half ahead
            HALF(sa, q)
            LOADXS(sa, q + 2)
            HALF(sb, q + 1)
        }
        // peeled tail (q = 14, 15): no wrap arithmetic, no redundant prefetch
        LOADXS(sb, 15)
        HALF(sa, 14)
        HALF(sb, 15)

        // fence: keep epilogue (ne4) loads OUT of the q-loop's liveness
        __builtin_amdgcn_sched_barrier(0);

        // epilogue: ne loaded here only (L1-hot after first iter). Code id of
        // acc[ck][mt][r] = code0 + mt*32 + 4*kg + (r&3) + 8*(r>>2); (mt,r)
        // ascending <=> id ascending; strict < => first(lowest-index)-wins.
        f32x4v ne4[2][4];
        #pragma unroll
        for (int mt = 0; mt < 2; ++mt)
            #pragma unroll
            for (int g2 = 0; g2 < 4; ++g2)
                ne4[mt][g2] = *(const f32x4v*)(neF + code0 + mt * 32 + g2 * 8 + 4 * kg);
        #pragma unroll
        for (int ck = 0; ck < 2; ++ck) {
            float best = 3.402823466e+38f;
            int   bi   = 0;
            #pragma unroll
            for (int mt = 0; mt < 2; ++mt)
                #pragma unroll
                for (int r = 0; r < 16; ++r) {
                    float d  = acc[ck][mt][r] + ne4[mt][r >> 2][r & 3];
                    int   id = code0 + mt * 32 + 4 * kg + ((r & 3) + 8 * (r >> 2));
                    if (d < best) { best = d; bi = id; }
                }
            float ov = __shfl_xor(best, 32, 64);
            int   oi = __shfl_xor(bi, 32, 64);
            if (ov < best || (ov == best && oi < bi)) { best = ov; bi = oi; }
            if (kg == 0) {
                int row = (rb0 + ck) * 32 + c32;
                unsigned u = __float_as_uint(best);
                u = (u & 0x80000000u) ? ~u : (u | 0x80000000u);   // total-order map
                atomicMin(&minpair[row],
                          (((unsigned long long)u) << 32) | (unsigned)bi);
            }
        }
    }
}

// decode packed min, gather codebook row, write quantized_sg + float index,
// histogram atomic + per-block SSE partials.
__global__ __launch_bounds__(256) void finalize_kernel(
    const float* __restrict__ x, const float* __restrict__ emb,
    const unsigned long long* __restrict__ minpair,
    float* __restrict__ out_q, float* __restrict__ out_idx,
    int* __restrict__ counts, float* __restrict__ parts) {
    __shared__ float rde[4], rdq[4];
    int wv   = threadIdx.x >> 6;
    int row  = (blockIdx.x << 2) + wv;
    int lane = threadIdx.x & 63;

    int bi = (int)(minpair[row] & 0xFFFFFFFFull);

    float4 xv = ((const float4*)(x   + (size_t)row * DDIM))[lane];
    float4 ev = ((const float4*)(emb + (size_t)bi  * DDIM))[lane];
    float4 q;
    q.x = xv.x + (ev.x - xv.x);
    q.y = xv.y + (ev.y - xv.y);
    q.z = xv.z + (ev.z - xv.z);
    q.w = xv.w + (ev.w - xv.w);
    ((float4*)(out_q + (size_t)row * DDIM))[lane] = q;

    float de = (ev.x - xv.x) * (ev.x - xv.x) + (ev.y - xv.y) * (ev.y - xv.y)
             + (ev.z - xv.z) * (ev.z - xv.z) + (ev.w - xv.w) * (ev.w - xv.w);
    float dq = (q.x - ev.x) * (q.x - ev.x) + (q.y - ev.y) * (q.y - ev.y)
             + (q.z - ev.z) * (q.z - ev.z) + (q.w - ev.w) * (q.w - ev.w);
    #pragma unroll
    for (int m = 32; m; m >>= 1) {
        de += __shfl_xor(de, m, 64);
        dq += __shfl_xor(dq, m, 64);
    }
    if (lane == 0) {
        out_idx[row] = (float)bi;
        atomicAdd(&counts[bi], 1);
        rde[wv] = de; rdq[wv] = dq;
    }
    __syncthreads();
    if (threadIdx.x == 0) {
        parts[blockIdx.x]        = rde[0] + rde[1] + rde[2] + rde[3];
        parts[4096 + blockIdx.x] = rdq[0] + rdq[1] + rdq[2] + rdq[3];
    }
}

__global__ __launch_bounds__(256) void scalars_kernel(
    const int* __restrict__ counts, const float* __restrict__ parts,
    float* __restrict__ out_loss, float* __restrict__ out_perp) {
    __shared__ float red[256], rde[256], rdq[256];
    float local = 0.0f, de = 0.0f, dq = 0.0f;
    for (int k = threadIdx.x; k < KCODES; k += 256) {
        float p = (float)counts[k] * (1.0f / (float)ND_ROWS);
        local += p * logf(p + 1e-10f);
    }
    for (int k = threadIdx.x; k < 4096; k += 256) {
        de += parts[k];
        dq += parts[4096 + k];
    }
    red[threadIdx.x] = local; rde[threadIdx.x] = de; rdq[threadIdx.x] = dq;
    __syncthreads();
    for (int s = 128; s; s >>= 1) {
        if (threadIdx.x < s) {
            red[threadIdx.x] += red[threadIdx.x + s];
            rde[threadIdx.x] += rde[threadIdx.x + s];
            rdq[threadIdx.x] += rdq[threadIdx.x + s];
        }
        __syncthreads();
    }
    if (threadIdx.x == 0) {
        *out_perp = expf(-red[0]);
        float invn = 1.0f / (float)(ND_ROWS * DDIM);
        *out_loss = rdq[0] * invn + 0.25f * (rde[0] * invn);
    }
}

extern "C" void kernel_launch(void* const* d_in, const int* in_sizes, int n_in,
                              void* d_out, int out_size, void* d_ws, size_t ws_size,
                              hipStream_t stream) {
    const float* x   = (const float*)d_in[0];
    const float* emb = (const float*)d_in[1];

    char* ws = (char*)d_ws;
    unsigned long long* minpair = (unsigned long long*)ws;         // 128 KB
    int*      counts = (int*)(ws + 131072);                        // 32 KB
    float*    parts  = (float*)(ws + 163840);                      // 32 KB
    float*    neF    = (float*)(ws + 196608);                      // 32 KB
    _Float16* Xp     = (_Float16*)(ws + 229376);                   // 16.8 MB
    _Float16* Bp     = (_Float16*)(ws + 17006592);                 // 8.4 MB

    float* out_q    = (float*)d_out;
    float* out_idx  = out_q + (size_t)ND_ROWS * DDIM;
    float* out_loss = out_idx + ND_ROWS;
    float* out_perp = out_loss + 1;

    prep_kernel<<<(KCODES + ND_ROWS) / 4, 256, 0, stream>>>(x, emb, Xp, Bp, neF,
                                                            minpair, counts);
    argmin_seg<<<NRG * NSEG, 512, 0, stream>>>(Xp, Bp, neF, minpair);
    finalize_kernel<<<ND_ROWS / 4, 256, 0, stream>>>(x, emb, minpair,
                                                     out_q, out_idx, counts, parts);
    scalars_kernel<<<1, 256, 0, stream>>>(counts, parts, out_loss, out_perp);
}

// Round 10
// 307.737 us; speedup vs baseline: 1.3578x; 1.0409x over previous
//
#include <hip/hip_runtime.h>
#include <math.h>
#include <stdint.h>

#define ND_ROWS 16384
#define DDIM    256
#define KCODES  8192
#define NSEG    128        // 64-code segments
#define NRG     8          // row groups (XCD-affine), 2048 rows each

typedef _Float16 f16x4 __attribute__((ext_vector_type(4)));
typedef _Float16 f16x8 __attribute__((ext_vector_type(8)));
typedef float    f32x4v __attribute__((ext_vector_type(4)));
typedef float    f32x16 __attribute__((ext_vector_type(16)));

// R20: consolidation + coalesced prep.
//  - argmin: EXACT R14/R17 version (best measured: 211.5 us, FETCH 60 MB,
//    0 bank conflicts, no spill). Pipeline variants R12/13/15/16/18/19 all
//    spilled or were occupancy-neutral; the 44% MfmaUtil wall stands.
//  - prep x-part: one block per 32-row rb. Old: wave-per-row scattered 8 B
//    global stores (fragment layout interleaves 32 rows -> ~8-16x write
//    amplification on 16.8 MB). New: scatter into 32 KB LDS (free), then
//    LDS->global LINEAR copy (LDS layout == output layout). Bit-identical.
//  - memset-free init kept; 4 dispatches; no fence fusion (R17 lesson).
// ---------------------------------------------------------------------------
// ws layout (bytes):
//   minpair [0,        131072)   u64[16384]  (init by prep)
//   counts  [131072,   163840)   int[8192]   (init by prep)
//   parts   [163840,   196608)   de[4096] | dq[4096]
//   neF     [196608,   229376)   float[8192] = ||e||^2
//   Xp      [229376,   17006592) x as MFMA B-operand fragments, 16.8 MB:
//            per 32-row block rb (32 KB): hi q=0..15 then lo q=0..15; unit
//            (rb,q) = 1 KB; 16B chunk index within unit = (kg<<5)|rl holding
//            halves k = q*16 + kg*8 .. +8 of row rl.
//   Bp      [17006592, 25395200) 8192 x 512 f16 = [-2e_hi(256) | -2e_lo(256)]
// ---------------------------------------------------------------------------

__device__ __attribute__((always_inline)) inline void load_lds16(const void* g, void* l) {
    __builtin_amdgcn_global_load_lds((const __attribute__((address_space(1))) void*)g,
                                     (__attribute__((address_space(3))) void*)l, 16, 0, 0);
}

// Blocks 0..511: x-transpose blocks (one rb = 32 rows each; LDS-staged,
// coalesced global I/O). Blocks 512..2559: emb wave-per-row (unchanged).
__global__ __launch_bounds__(256) void prep_kernel(const float* __restrict__ x,
                                                   const float* __restrict__ emb,
                                                   _Float16* __restrict__ Xp,
                                                   _Float16* __restrict__ Bp,
                                                   float* __restrict__ neF,
                                                   unsigned long long* __restrict__ minpair,
                                                   int* __restrict__ counts) {
    __shared__ __align__(16) _Float16 S[16384];   // 32 KB staging (x-blocks)
    const int bid = blockIdx.x;
    const int tid = threadIdx.x;

    if (bid < 512) {
        // ---- x part: rb = bid, rows rb*32 .. +32 ----
        const int rb = bid;
        const float4* src = (const float4*)(x + (size_t)rb * 32 * DDIM); // 2048 float4
        #pragma unroll
        for (int i = 0; i < 8; ++i) {
            int g = i * 256 + tid;           // float4 index within the rb block
            float4 v = src[g];
            int rl = g >> 6;                 // row 0..31
            int k0 = (g & 63) << 2;          // k = k0 .. k0+3
            f16x4 hi, lo;
            hi[0] = (_Float16)v.x; lo[0] = (_Float16)(v.x - (float)hi[0]);
            hi[1] = (_Float16)v.y; lo[1] = (_Float16)(v.y - (float)hi[1]);
            hi[2] = (_Float16)v.z; lo[2] = (_Float16)(v.z - (float)hi[2]);
            hi[3] = (_Float16)v.w; lo[3] = (_Float16)(v.w - (float)hi[3]);
            // fragment offset (f16 units): q*512 + kg*256 + rl*8 + j0*4
            int off = ((k0 >> 4) << 9) + (((k0 >> 3) & 1) << 8)
                    + (rl << 3) + (((k0 >> 2) & 1) << 2);
            *(f16x4*)(S + off)        = hi;      // hi half [0, 8192)
            *(f16x4*)(S + off + 8192) = lo;      // lo half [8192, 16384)
        }
        if (tid < 32) minpair[rb * 32 + tid] = 0xFFFFFFFFFFFFFFFFull;
        __syncthreads();
        // LDS layout == output layout: straight coalesced copy (32 KB)
        float4* dst = (float4*)(Xp + (size_t)rb * 16384);
        const float4* sls = (const float4*)S;
        #pragma unroll
        for (int i = 0; i < 8; ++i) {
            int g = i * 256 + tid;
            dst[g] = sls[g];
        }
    } else {
        // ---- emb part: wave per codebook row ----
        int wave = ((bid - 512) << 2) + (tid >> 6);   // 0..8191
        int lane = tid & 63;
        int r    = wave;
        const float* src = emb + (size_t)r * DDIM;
        float4 v = ((const float4*)src)[lane];
        float s = v.x*v.x + v.y*v.y + v.z*v.z + v.w*v.w;  // ||e||^2 of original e
        #pragma unroll
        for (int m = 32; m; m >>= 1) s += __shfl_xor(s, m, 64);
        float4 t;                                         // fold the -2 in
        t.x = -2.0f * v.x; t.y = -2.0f * v.y; t.z = -2.0f * v.z; t.w = -2.0f * v.w;
        f16x4 hi, lo;
        hi[0] = (_Float16)t.x; lo[0] = (_Float16)(t.x - (float)hi[0]);
        hi[1] = (_Float16)t.y; lo[1] = (_Float16)(t.y - (float)hi[1]);
        hi[2] = (_Float16)t.z; lo[2] = (_Float16)(t.z - (float)hi[2]);
        hi[3] = (_Float16)t.w; lo[3] = (_Float16)(t.w - (float)hi[3]);
        _Float16* dst = Bp + (size_t)r * 512;
        *(f16x4*)(dst + lane * 4)       = hi;
        *(f16x4*)(dst + 256 + lane * 4) = lo;
        if (lane == 0) {
            neF[r] = s;
            counts[r] = 0;
        }
    }
}

// Barrier-free argmin GEMM, codes-as-M, mfma_f32_32x32x16_f16, 2-chunk blocked.
// EXACT R14/R17 structure (best measured): acc[2][2], unroll 2, launch_bounds
// (512,4), transposed conflict-free code slab, JIT loads, no setprio.
#define MFMA16(A, B, C) __builtin_amdgcn_mfma_f32_32x32x16_f16(A, B, C, 0, 0, 0)

__global__ __launch_bounds__(512, 4) void argmin_seg(
    const _Float16* __restrict__ Xp, const _Float16* __restrict__ Bp,
    const float* __restrict__ neF, unsigned long long* __restrict__ minpair) {
    __shared__ __align__(16) _Float16 Cs[64 * 512];   // 64 KB, nothing else

    const int tid  = threadIdx.x;
    const int lane = tid & 63;
    const int w    = tid >> 6;     // 0..7
    const int c32  = lane & 31;
    const int kg   = lane >> 5;

    const int rg      = blockIdx.x & 7;
    const int seg     = blockIdx.x >> 3;
    const int rowBase = rg * 2048;
    const int code0   = seg * 64;

    // stage code slab TRANSPOSED: LDS chunk j (1 KB, linear dest) holds
    // { slot 2*(j&31)+0 : codes 0..31 | slot 2*(j&31)+1 : codes 0..31 } of
    // code-half (j>>5). Lane l fetches global Bp[code0 + (j&32) + (l&31)]
    // slot (2*(j&31) + (l>>5)).  (16B-gather src; prologue-only, L2-hot.)
    #pragma unroll
    for (int i = 0; i < 8; ++i) {
        int j    = w * 8 + i;
        int code = code0 + (j & 32) + (lane & 31);
        int s    = ((j & 31) << 1) | (lane >> 5);
        load_lds16((const char*)Bp + ((size_t)code << 10) + (s << 4),
                   (char*)Cs + (j << 10));
    }
    __syncthreads();   // the only barrier

    // read base: lane offset c32*16 within a 512B slot-row, kg picks the
    // adjacent slot. Per q: 4 reads at compile-time offsets, each wave-
    // contiguous 1 KB -> conflict-free.
    const char* cpb = (const char*)Cs + (kg << 9) + (c32 << 4);

    const int wBase = rowBase + w * 256;   // 4 chunk-pairs of 64 rows per wave
    for (int c2 = 0; c2 < 4; ++c2) {
        const int rb0 = (wBase >> 5) + c2 * 2;
        const char* xb0 = (const char*)Xp + (size_t)rb0 * 32768 + lane * 16;
        const char* xb1 = xb0 + 32768;
        f32x16 acc[2][2];   // [chunk][mt] - 4 independent MFMA chains, 64 AGPR
        #pragma unroll
        for (int i = 0; i < 16; ++i) {
            acc[0][0][i] = 0.0f; acc[0][1][i] = 0.0f;
            acc[1][0][i] = 0.0f; acc[1][1][i] = 0.0f;
        }

        #pragma unroll 2
        for (int q = 0; q < 16; ++q) {
            f16x8 xh0 = *(const f16x8*)(xb0 + q * 1024);
            f16x8 xl0 = *(const f16x8*)(xb0 + 16384 + q * 1024);
            f16x8 xh1 = *(const f16x8*)(xb1 + q * 1024);
            f16x8 xl1 = *(const f16x8*)(xb1 + 16384 + q * 1024);
            f16x8 ch0 = *(const f16x8*)(cpb + q * 1024);
            f16x8 cl0 = *(const f16x8*)(cpb + 16384 + q * 1024);
            f16x8 ch1 = *(const f16x8*)(cpb + 32768 + q * 1024);
            f16x8 cl1 = *(const f16x8*)(cpb + 49152 + q * 1024);
            // 12 MFMAs, chain-interleaved (each chain's next issue is 4 slots away)
            acc[0][0] = MFMA16(ch0, xh0, acc[0][0]);
            acc[0][1] = MFMA16(ch1, xh0, acc[0][1]);
            acc[1][0] = MFMA16(ch0, xh1, acc[1][0]);
            acc[1][1] = MFMA16(ch1, xh1, acc[1][1]);
            acc[0][0] = MFMA16(ch0, xl0, acc[0][0]);
            acc[0][1] = MFMA16(ch1, xl0, acc[0][1]);
            acc[1][0] = MFMA16(ch0, xl1, acc[1][0]);
            acc[1][1] = MFMA16(ch1, xl1, acc[1][1]);
            acc[0][0] = MFMA16(cl0, xh0, acc[0][0]);
            acc[0][1] = MFMA16(cl1, xh0, acc[0][1]);
            acc[1][0] = MFMA16(cl0, xh1, acc[1][0]);
            acc[1][1] = MFMA16(cl1, xh1, acc[1][1]);
        }

        // epilogue: ne loaded here only (L1-hot after first iter). Code id of
        // acc[ck][mt][r] = code0 + mt*32 + 4*kg + (r&3) + 8*(r>>2); (mt,r)
        // ascending <=> id ascending; strict < => first(lowest-index)-wins.
        f32x4v ne4[2][4];
        #pragma unroll
        for (int mt = 0; mt < 2; ++mt)
            #pragma unroll
            for (int g2 = 0; g2 < 4; ++g2)
                ne4[mt][g2] = *(const f32x4v*)(neF + code0 + mt * 32 + g2 * 8 + 4 * kg);
        #pragma unroll
        for (int ck = 0; ck < 2; ++ck) {
            float best = 3.402823466e+38f;
            int   bi   = 0;
            #pragma unroll
            for (int mt = 0; mt < 2; ++mt)
                #pragma unroll
                for (int r = 0; r < 16; ++r) {
                    float d  = acc[ck][mt][r] + ne4[mt][r >> 2][r & 3];
                    int   id = code0 + mt * 32 + 4 * kg + ((r & 3) + 8 * (r >> 2));
                    if (d < best) { best = d; bi = id; }
                }
            float ov = __shfl_xor(best, 32, 64);
            int   oi = __shfl_xor(bi, 32, 64);
            if (ov < best || (ov == best && oi < bi)) { best = ov; bi = oi; }
            if (kg == 0) {
                int row = (rb0 + ck) * 32 + c32;
                unsigned u = __float_as_uint(best);
                u = (u & 0x80000000u) ? ~u : (u | 0x80000000u);   // total-order map
                atomicMin(&minpair[row],
                          (((unsigned long long)u) << 32) | (unsigned)bi);
            }
        }
    }
}

// decode packed min, gather codebook row, write quantized_sg + float index,
// histogram atomic + per-block SSE partials.
__global__ __launch_bounds__(256) void finalize_kernel(
    const float* __restrict__ x, const float* __restrict__ emb,
    const unsigned long long* __restrict__ minpair,
    float* __restrict__ out_q, float* __restrict__ out_idx,
    int* __restrict__ counts, float* __restrict__ parts) {
    __shared__ float rde[4], rdq[4];
    int wv   = threadIdx.x >> 6;
    int row  = (blockIdx.x << 2) + wv;
    int lane = threadIdx.x & 63;

    int bi = (int)(minpair[row] & 0xFFFFFFFFull);

    float4 xv = ((const float4*)(x   + (size_t)row * DDIM))[lane];
    float4 ev = ((const float4*)(emb + (size_t)bi  * DDIM))[lane];
    float4 q;
    q.x = xv.x + (ev.x - xv.x);
    q.y = xv.y + (ev.y - xv.y);
    q.z = xv.z + (ev.z - xv.z);
    q.w = xv.w + (ev.w - xv.w);
    ((float4*)(out_q + (size_t)row * DDIM))[lane] = q;

    float de = (ev.x - xv.x) * (ev.x - xv.x) + (ev.y - xv.y) * (ev.y - xv.y)
             + (ev.z - xv.z) * (ev.z - xv.z) + (ev.w - xv.w) * (ev.w - xv.w);
    float dq = (q.x - ev.x) * (q.x - ev.x) + (q.y - ev.y) * (q.y - ev.y)
             + (q.z - ev.z) * (q.z - ev.z) + (q.w - ev.w) * (q.w - ev.w);
    #pragma unroll
    for (int m = 32; m; m >>= 1) {
        de += __shfl_xor(de, m, 64);
        dq += __shfl_xor(dq, m, 64);
    }
    if (lane == 0) {
        out_idx[row] = (float)bi;
        atomicAdd(&counts[bi], 1);
        rde[wv] = de; rdq[wv] = dq;
    }
    __syncthreads();
    if (threadIdx.x == 0) {
        parts[blockIdx.x]        = rde[0] + rde[1] + rde[2] + rde[3];
        parts[4096 + blockIdx.x] = rdq[0] + rdq[1] + rdq[2] + rdq[3];
    }
}

__global__ __launch_bounds__(256) void scalars_kernel(
    const int* __restrict__ counts, const float* __restrict__ parts,
    float* __restrict__ out_loss, float* __restrict__ out_perp) {
    __shared__ float red[256], rde[256], rdq[256];
    float local = 0.0f, de = 0.0f, dq = 0.0f;
    for (int k = threadIdx.x; k < KCODES; k += 256) {
        float p = (float)counts[k] * (1.0f / (float)ND_ROWS);
        local += p * logf(p + 1e-10f);
    }
    for (int k = threadIdx.x; k < 4096; k += 256) {
        de += parts[k];
        dq += parts[4096 + k];
    }
    red[threadIdx.x] = local; rde[threadIdx.x] = de; rdq[threadIdx.x] = dq;
    __syncthreads();
    for (int s = 128; s; s >>= 1) {
        if (threadIdx.x < s) {
            red[threadIdx.x] += red[threadIdx.x + s];
            rde[threadIdx.x] += rde[threadIdx.x + s];
            rdq[threadIdx.x] += rdq[threadIdx.x + s];
        }
        __syncthreads();
    }
    if (threadIdx.x == 0) {
        *out_perp = expf(-red[0]);
        float invn = 1.0f / (float)(ND_ROWS * DDIM);
        *out_loss = rdq[0] * invn + 0.25f * (rde[0] * invn);
    }
}

extern "C" void kernel_launch(void* const* d_in, const int* in_sizes, int n_in,
                              void* d_out, int out_size, void* d_ws, size_t ws_size,
                              hipStream_t stream) {
    const float* x   = (const float*)d_in[0];
    const float* emb = (const float*)d_in[1];

    char* ws = (char*)d_ws;
    unsigned long long* minpair = (unsigned long long*)ws;         // 128 KB
    int*      counts = (int*)(ws + 131072);                        // 32 KB
    float*    parts  = (float*)(ws + 163840);                      // 32 KB
    float*    neF    = (float*)(ws + 196608);                      // 32 KB
    _Float16* Xp     = (_Float16*)(ws + 229376);                   // 16.8 MB
    _Float16* Bp     = (_Float16*)(ws + 17006592);                 // 8.4 MB

    float* out_q    = (float*)d_out;
    float* out_idx  = out_q + (size_t)ND_ROWS * DDIM;
    float* out_loss = out_idx + ND_ROWS;
    float* out_perp = out_loss + 1;

    prep_kernel<<<512 + KCODES / 4, 256, 0, stream>>>(x, emb, Xp, Bp, neF,
                                                      minpair, counts);
    argmin_seg<<<NRG * NSEG, 512, 0, stream>>>(Xp, Bp, neF, minpair);
    finalize_kernel<<<ND_ROWS / 4, 256, 0, stream>>>(x, emb, minpair,
                                                     out_q, out_idx, counts, parts);
    scalars_kernel<<<1, 256, 0, stream>>>(counts, parts, out_loss, out_perp);
}

// Round 11
// 307.268 us; speedup vs baseline: 1.3599x; 1.0015x over previous
//
#include <hip/hip_runtime.h>
#include <math.h>
#include <stdint.h>

#define ND_ROWS 16384
#define DDIM    256
#define KCODES  8192
#define NSEG    128        // 64-code segments (2 per block)
#define NRG     8          // row groups (XCD-affine), 2048 rows each

typedef _Float16 f16x4 __attribute__((ext_vector_type(4)));
typedef _Float16 f16x8 __attribute__((ext_vector_type(8)));
typedef float    f32x4v __attribute__((ext_vector_type(4)));
typedef float    f32x16 __attribute__((ext_vector_type(16)));

// R21: single-batch argmin grid (1024 -> 512 blocks, 2 segments per block).
// Post-mortem R20: argmin Occupancy 37% vs the 50% the register/LDS math
// allows (64V+64A=128 regs -> 4 waves/SIMD; 64KB LDS -> 2 blocks/CU). The
// gap is the 2-batch grid drain: 1024 blocks = 2 sequential waves of 512
// resident, each with a straggler tail + cold-L2 restart. Fix: 512 blocks,
// each processing 2 consecutive segments with an LDS slab swap (barrier ->
// re-stage -> barrier). Same per-wave shape; one drain; warm-L2 pass B.
// prep: R20 LDS-staged coalesced transpose (kept). 4 dispatches, no fences.
// ---------------------------------------------------------------------------
// ws layout (bytes):
//   minpair [0,        131072)   u64[16384]  (init by prep)
//   counts  [131072,   163840)   int[8192]   (init by prep)
//   parts   [163840,   196608)   de[4096] | dq[4096]
//   neF     [196608,   229376)   float[8192] = ||e||^2
//   Xp      [229376,   17006592) x as MFMA B-operand fragments, 16.8 MB:
//            per 32-row block rb (32 KB): hi q=0..15 then lo q=0..15; unit
//            (rb,q) = 1 KB; 16B chunk index within unit = (kg<<5)|rl holding
//            halves k = q*16 + kg*8 .. +8 of row rl.
//   Bp      [17006592, 25395200) 8192 x 512 f16 = [-2e_hi(256) | -2e_lo(256)]
// ---------------------------------------------------------------------------

__device__ __attribute__((always_inline)) inline void load_lds16(const void* g, void* l) {
    __builtin_amdgcn_global_load_lds((const __attribute__((address_space(1))) void*)g,
                                     (__attribute__((address_space(3))) void*)l, 16, 0, 0);
}

// Blocks 0..511: x-transpose blocks (one rb = 32 rows each; LDS-staged,
// coalesced global I/O). Blocks 512..2559: emb wave-per-row.
__global__ __launch_bounds__(256) void prep_kernel(const float* __restrict__ x,
                                                   const float* __restrict__ emb,
                                                   _Float16* __restrict__ Xp,
                                                   _Float16* __restrict__ Bp,
                                                   float* __restrict__ neF,
                                                   unsigned long long* __restrict__ minpair,
                                                   int* __restrict__ counts) {
    __shared__ __align__(16) _Float16 S[16384];   // 32 KB staging (x-blocks)
    const int bid = blockIdx.x;
    const int tid = threadIdx.x;

    if (bid < 512) {
        // ---- x part: rb = bid, rows rb*32 .. +32 ----
        const int rb = bid;
        const float4* src = (const float4*)(x + (size_t)rb * 32 * DDIM); // 2048 float4
        #pragma unroll
        for (int i = 0; i < 8; ++i) {
            int g = i * 256 + tid;           // float4 index within the rb block
            float4 v = src[g];
            int rl = g >> 6;                 // row 0..31
            int k0 = (g & 63) << 2;          // k = k0 .. k0+3
            f16x4 hi, lo;
            hi[0] = (_Float16)v.x; lo[0] = (_Float16)(v.x - (float)hi[0]);
            hi[1] = (_Float16)v.y; lo[1] = (_Float16)(v.y - (float)hi[1]);
            hi[2] = (_Float16)v.z; lo[2] = (_Float16)(v.z - (float)hi[2]);
            hi[3] = (_Float16)v.w; lo[3] = (_Float16)(v.w - (float)hi[3]);
            // fragment offset (f16 units): q*512 + kg*256 + rl*8 + j0*4
            int off = ((k0 >> 4) << 9) + (((k0 >> 3) & 1) << 8)
                    + (rl << 3) + (((k0 >> 2) & 1) << 2);
            *(f16x4*)(S + off)        = hi;      // hi half [0, 8192)
            *(f16x4*)(S + off + 8192) = lo;      // lo half [8192, 16384)
        }
        if (tid < 32) minpair[rb * 32 + tid] = 0xFFFFFFFFFFFFFFFFull;
        __syncthreads();
        // LDS layout == output layout: straight coalesced copy (32 KB)
        float4* dst = (float4*)(Xp + (size_t)rb * 16384);
        const float4* sls = (const float4*)S;
        #pragma unroll
        for (int i = 0; i < 8; ++i) {
            int g = i * 256 + tid;
            dst[g] = sls[g];
        }
    } else {
        // ---- emb part: wave per codebook row ----
        int wave = ((bid - 512) << 2) + (tid >> 6);   // 0..8191
        int lane = tid & 63;
        int r    = wave;
        const float* src = emb + (size_t)r * DDIM;
        float4 v = ((const float4*)src)[lane];
        float s = v.x*v.x + v.y*v.y + v.z*v.z + v.w*v.w;  // ||e||^2 of original e
        #pragma unroll
        for (int m = 32; m; m >>= 1) s += __shfl_xor(s, m, 64);
        float4 t;                                         // fold the -2 in
        t.x = -2.0f * v.x; t.y = -2.0f * v.y; t.z = -2.0f * v.z; t.w = -2.0f * v.w;
        f16x4 hi, lo;
        hi[0] = (_Float16)t.x; lo[0] = (_Float16)(t.x - (float)hi[0]);
        hi[1] = (_Float16)t.y; lo[1] = (_Float16)(t.y - (float)hi[1]);
        hi[2] = (_Float16)t.z; lo[2] = (_Float16)(t.z - (float)hi[2]);
        hi[3] = (_Float16)t.w; lo[3] = (_Float16)(t.w - (float)hi[3]);
        _Float16* dst = Bp + (size_t)r * 512;
        *(f16x4*)(dst + lane * 4)       = hi;
        *(f16x4*)(dst + 256 + lane * 4) = lo;
        if (lane == 0) {
            neF[r] = s;
            counts[r] = 0;
        }
    }
}

// Barrier-free-main-loop argmin GEMM, codes-as-M, mfma_f32_32x32x16_f16.
// R14 per-segment structure (acc[2][2], unroll 2, 512x4, transposed
// conflict-free slab, JIT loads); R21: 2 segments per block via slab swap.
#define MFMA16(A, B, C) __builtin_amdgcn_mfma_f32_32x32x16_f16(A, B, C, 0, 0, 0)

__global__ __launch_bounds__(512, 4) void argmin_seg(
    const _Float16* __restrict__ Xp, const _Float16* __restrict__ Bp,
    const float* __restrict__ neF, unsigned long long* __restrict__ minpair) {
    __shared__ __align__(16) _Float16 Cs[64 * 512];   // 64 KB, nothing else

    const int tid  = threadIdx.x;
    const int lane = tid & 63;
    const int w    = tid >> 6;     // 0..7
    const int c32  = lane & 31;
    const int kg   = lane >> 5;

    const int rg      = blockIdx.x & 7;
    const int segBase = (blockIdx.x >> 3) << 1;   // 2 consecutive segments
    const int rowBase = rg * 2048;

    // read base: lane offset c32*16 within a 512B slot-row, kg picks the
    // adjacent slot. Per q: 4 reads at compile-time offsets, each wave-
    // contiguous 1 KB -> conflict-free.
    const char* cpb = (const char*)Cs + (kg << 9) + (c32 << 4);
    const int wBase = rowBase + w * 256;   // 4 chunk-pairs of 64 rows per wave

    #pragma unroll 1
    for (int pass = 0; pass < 2; ++pass) {
        const int code0 = (segBase + pass) * 64;

        if (pass) __syncthreads();   // all waves done reading previous slab

        // stage code slab TRANSPOSED: LDS chunk j (1 KB, linear dest) holds
        // { slot 2*(j&31)+0 : codes 0..31 | slot 2*(j&31)+1 : codes 0..31 }
        // of code-half (j>>5). Lane l fetches Bp[code0 + (j&32) + (l&31)]
        // slot (2*(j&31) + (l>>5)). (16B-gather src; L2-hot.)
        #pragma unroll
        for (int i = 0; i < 8; ++i) {
            int j    = w * 8 + i;
            int code = code0 + (j & 32) + (lane & 31);
            int s    = ((j & 31) << 1) | (lane >> 5);
            load_lds16((const char*)Bp + ((size_t)code << 10) + (s << 4),
                       (char*)Cs + (j << 10));
        }
        __syncthreads();

        for (int c2 = 0; c2 < 4; ++c2) {
            const int rb0 = (wBase >> 5) + c2 * 2;
            const char* xb0 = (const char*)Xp + (size_t)rb0 * 32768 + lane * 16;
            const char* xb1 = xb0 + 32768;
            f32x16 acc[2][2];   // [chunk][mt] - 4 independent MFMA chains, 64 AGPR
            #pragma unroll
            for (int i = 0; i < 16; ++i) {
                acc[0][0][i] = 0.0f; acc[0][1][i] = 0.0f;
                acc[1][0][i] = 0.0f; acc[1][1][i] = 0.0f;
            }

            #pragma unroll 2
            for (int q = 0; q < 16; ++q) {
                f16x8 xh0 = *(const f16x8*)(xb0 + q * 1024);
                f16x8 xl0 = *(const f16x8*)(xb0 + 16384 + q * 1024);
                f16x8 xh1 = *(const f16x8*)(xb1 + q * 1024);
                f16x8 xl1 = *(const f16x8*)(xb1 + 16384 + q * 1024);
                f16x8 ch0 = *(const f16x8*)(cpb + q * 1024);
                f16x8 cl0 = *(const f16x8*)(cpb + 16384 + q * 1024);
                f16x8 ch1 = *(const f16x8*)(cpb + 32768 + q * 1024);
                f16x8 cl1 = *(const f16x8*)(cpb + 49152 + q * 1024);
                // 12 MFMAs, chain-interleaved (next issue of a chain 4 slots away)
                acc[0][0] = MFMA16(ch0, xh0, acc[0][0]);
                acc[0][1] = MFMA16(ch1, xh0, acc[0][1]);
                acc[1][0] = MFMA16(ch0, xh1, acc[1][0]);
                acc[1][1] = MFMA16(ch1, xh1, acc[1][1]);
                acc[0][0] = MFMA16(ch0, xl0, acc[0][0]);
                acc[0][1] = MFMA16(ch1, xl0, acc[0][1]);
                acc[1][0] = MFMA16(ch0, xl1, acc[1][0]);
                acc[1][1] = MFMA16(ch1, xl1, acc[1][1]);
                acc[0][0] = MFMA16(cl0, xh0, acc[0][0]);
                acc[0][1] = MFMA16(cl1, xh0, acc[0][1]);
                acc[1][0] = MFMA16(cl0, xh1, acc[1][0]);
                acc[1][1] = MFMA16(cl1, xh1, acc[1][1]);
            }

            // epilogue: ne loaded here only (L1-hot after first iter). Code id
            // of acc[ck][mt][r] = code0 + mt*32 + 4*kg + (r&3) + 8*(r>>2);
            // (mt,r) ascending <=> id ascending; strict < => first-wins.
            f32x4v ne4[2][4];
            #pragma unroll
            for (int mt = 0; mt < 2; ++mt)
                #pragma unroll
                for (int g2 = 0; g2 < 4; ++g2)
                    ne4[mt][g2] = *(const f32x4v*)(neF + code0 + mt * 32 + g2 * 8 + 4 * kg);
            #pragma unroll
            for (int ck = 0; ck < 2; ++ck) {
                float best = 3.402823466e+38f;
                int   bi   = 0;
                #pragma unroll
                for (int mt = 0; mt < 2; ++mt)
                    #pragma unroll
                    for (int r = 0; r < 16; ++r) {
                        float d  = acc[ck][mt][r] + ne4[mt][r >> 2][r & 3];
                        int   id = code0 + mt * 32 + 4 * kg + ((r & 3) + 8 * (r >> 2));
                        if (d < best) { best = d; bi = id; }
                    }
                float ov = __shfl_xor(best, 32, 64);
                int   oi = __shfl_xor(bi, 32, 64);
                if (ov < best || (ov == best && oi < bi)) { best = ov; bi = oi; }
                if (kg == 0) {
                    int row = (rb0 + ck) * 32 + c32;
                    unsigned u = __float_as_uint(best);
                    u = (u & 0x80000000u) ? ~u : (u | 0x80000000u);   // total-order map
                    atomicMin(&minpair[row],
                              (((unsigned long long)u) << 32) | (unsigned)bi);
                }
            }
        }
    }
}

// decode packed min, gather codebook row, write quantized_sg + float index,
// histogram atomic + per-block SSE partials.
__global__ __launch_bounds__(256) void finalize_kernel(
    const float* __restrict__ x, const float* __restrict__ emb,
    const unsigned long long* __restrict__ minpair,
    float* __restrict__ out_q, float* __restrict__ out_idx,
    int* __restrict__ counts, float* __restrict__ parts) {
    __shared__ float rde[4], rdq[4];
    int wv   = threadIdx.x >> 6;
    int row  = (blockIdx.x << 2) + wv;
    int lane = threadIdx.x & 63;

    int bi = (int)(minpair[row] & 0xFFFFFFFFull);

    float4 xv = ((const float4*)(x   + (size_t)row * DDIM))[lane];
    float4 ev = ((const float4*)(emb + (size_t)bi  * DDIM))[lane];
    float4 q;
    q.x = xv.x + (ev.x - xv.x);
    q.y = xv.y + (ev.y - xv.y);
    q.z = xv.z + (ev.z - xv.z);
    q.w = xv.w + (ev.w - xv.w);
    ((float4*)(out_q + (size_t)row * DDIM))[lane] = q;

    float de = (ev.x - xv.x) * (ev.x - xv.x) + (ev.y - xv.y) * (ev.y - xv.y)
             + (ev.z - xv.z) * (ev.z - xv.z) + (ev.w - xv.w) * (ev.w - xv.w);
    float dq = (q.x - ev.x) * (q.x - ev.x) + (q.y - ev.y) * (q.y - ev.y)
             + (q.z - ev.z) * (q.z - ev.z) + (q.w - ev.w) * (q.w - ev.w);
    #pragma unroll
    for (int m = 32; m; m >>= 1) {
        de += __shfl_xor(de, m, 64);
        dq += __shfl_xor(dq, m, 64);
    }
    if (lane == 0) {
        out_idx[row] = (float)bi;
        atomicAdd(&counts[bi], 1);
        rde[wv] = de; rdq[wv] = dq;
    }
    __syncthreads();
    if (threadIdx.x == 0) {
        parts[blockIdx.x]        = rde[0] + rde[1] + rde[2] + rde[3];
        parts[4096 + blockIdx.x] = rdq[0] + rdq[1] + rdq[2] + rdq[3];
    }
}

__global__ __launch_bounds__(256) void scalars_kernel(
    const int* __restrict__ counts, const float* __restrict__ parts,
    float* __restrict__ out_loss, float* __restrict__ out_perp) {
    __shared__ float red[256], rde[256], rdq[256];
    float local = 0.0f, de = 0.0f, dq = 0.0f;
    for (int k = threadIdx.x; k < KCODES; k += 256) {
        float p = (float)counts[k] * (1.0f / (float)ND_ROWS);
        local += p * logf(p + 1e-10f);
    }
    for (int k = threadIdx.x; k < 4096; k += 256) {
        de += parts[k];
        dq += parts[4096 + k];
    }
    red[threadIdx.x] = local; rde[threadIdx.x] = de; rdq[threadIdx.x] = dq;
    __syncthreads();
    for (int s = 128; s; s >>= 1) {
        if (threadIdx.x < s) {
            red[threadIdx.x] += red[threadIdx.x + s];
            rde[threadIdx.x] += rde[threadIdx.x + s];
            rdq[threadIdx.x] += rdq[threadIdx.x + s];
        }
        __syncthreads();
    }
    if (threadIdx.x == 0) {
        *out_perp = expf(-red[0]);
        float invn = 1.0f / (float)(ND_ROWS * DDIM);
        *out_loss = rdq[0] * invn + 0.25f * (rde[0] * invn);
    }
}

extern "C" void kernel_launch(void* const* d_in, const int* in_sizes, int n_in,
                              void* d_out, int out_size, void* d_ws, size_t ws_size,
                              hipStream_t stream) {
    const float* x   = (const float*)d_in[0];
    const float* emb = (const float*)d_in[1];

    char* ws = (char*)d_ws;
    unsigned long long* minpair = (unsigned long long*)ws;         // 128 KB
    int*      counts = (int*)(ws + 131072);                        // 32 KB
    float*    parts  = (float*)(ws + 163840);                      // 32 KB
    float*    neF    = (float*)(ws + 196608);                      // 32 KB
    _Float16* Xp     = (_Float16*)(ws + 229376);                   // 16.8 MB
    _Float16* Bp     = (_Float16*)(ws + 17006592);                 // 8.4 MB

    float* out_q    = (float*)d_out;
    float* out_idx  = out_q + (size_t)ND_ROWS * DDIM;
    float* out_loss = out_idx + ND_ROWS;
    float* out_perp = out_loss + 1;

    prep_kernel<<<512 + KCODES / 4, 256, 0, stream>>>(x, emb, Xp, Bp, neF,
                                                      minpair, counts);
    argmin_seg<<<NRG * (NSEG / 2), 512, 0, stream>>>(Xp, Bp, neF, minpair);
    finalize_kernel<<<ND_ROWS / 4, 256, 0, stream>>>(x, emb, minpair,
                                                     out_q, out_idx, counts, parts);
    scalars_kernel<<<1, 256, 0, stream>>>(counts, parts, out_loss, out_perp);
}

// Round 12
// 301.926 us; speedup vs baseline: 1.3839x; 1.0177x over previous
//
#include <hip/hip_runtime.h>
#include <math.h>
#include <stdint.h>

#define ND_ROWS 16384
#define DDIM    256
#define KCODES  8192
#define NSEG    128        // 64-code segments
#define NRG     8          // row groups (XCD-affine), 2048 rows each

typedef _Float16 f16x4 __attribute__((ext_vector_type(4)));
typedef _Float16 f16x8 __attribute__((ext_vector_type(8)));
typedef float    f32x4v __attribute__((ext_vector_type(4)));
typedef float    f32x16 __attribute__((ext_vector_type(16)));

// R22: R20 exact (best measured: total 307.7, argmin 213.7 us) + ONE change:
// T5 s_setprio(1)/(0) around the 12-MFMA cluster.
// Post-mortem R21: 2-seg-per-block slab swap was neutral-to-negative (argmin
// 221 us, FETCH 60->100 MB: L2 reuse degraded more than the single-drain
// helped). Reverted to 1024-block grid.
// T5 rationale: catalog says setprio is null on barrier-synced lockstep GEMM
// (m190) but +4-7% where waves drift in distinct phases (m191). This argmin
// is barrier-free with 4 drifting waves/SIMD (MFMA-burst wave vs load-issue
// waves) -> role diversity present. Single-variable test.
// ---------------------------------------------------------------------------
// ws layout (bytes):
//   minpair [0,        131072)   u64[16384]  (init by prep)
//   counts  [131072,   163840)   int[8192]   (init by prep)
//   parts   [163840,   196608)   de[4096] | dq[4096]
//   neF     [196608,   229376)   float[8192] = ||e||^2
//   Xp      [229376,   17006592) x as MFMA B-operand fragments, 16.8 MB:
//            per 32-row block rb (32 KB): hi q=0..15 then lo q=0..15; unit
//            (rb,q) = 1 KB; 16B chunk index within unit = (kg<<5)|rl holding
//            halves k = q*16 + kg*8 .. +8 of row rl.
//   Bp      [17006592, 25395200) 8192 x 512 f16 = [-2e_hi(256) | -2e_lo(256)]
// ---------------------------------------------------------------------------

__device__ __attribute__((always_inline)) inline void load_lds16(const void* g, void* l) {
    __builtin_amdgcn_global_load_lds((const __attribute__((address_space(1))) void*)g,
                                     (__attribute__((address_space(3))) void*)l, 16, 0, 0);
}

// Blocks 0..511: x-transpose blocks (one rb = 32 rows each; LDS-staged,
// coalesced global I/O). Blocks 512..2559: emb wave-per-row.
__global__ __launch_bounds__(256) void prep_kernel(const float* __restrict__ x,
                                                   const float* __restrict__ emb,
                                                   _Float16* __restrict__ Xp,
                                                   _Float16* __restrict__ Bp,
                                                   float* __restrict__ neF,
                                                   unsigned long long* __restrict__ minpair,
                                                   int* __restrict__ counts) {
    __shared__ __align__(16) _Float16 S[16384];   // 32 KB staging (x-blocks)
    const int bid = blockIdx.x;
    const int tid = threadIdx.x;

    if (bid < 512) {
        // ---- x part: rb = bid, rows rb*32 .. +32 ----
        const int rb = bid;
        const float4* src = (const float4*)(x + (size_t)rb * 32 * DDIM); // 2048 float4
        #pragma unroll
        for (int i = 0; i < 8; ++i) {
            int g = i * 256 + tid;           // float4 index within the rb block
            float4 v = src[g];
            int rl = g >> 6;                 // row 0..31
            int k0 = (g & 63) << 2;          // k = k0 .. k0+3
            f16x4 hi, lo;
            hi[0] = (_Float16)v.x; lo[0] = (_Float16)(v.x - (float)hi[0]);
            hi[1] = (_Float16)v.y; lo[1] = (_Float16)(v.y - (float)hi[1]);
            hi[2] = (_Float16)v.z; lo[2] = (_Float16)(v.z - (float)hi[2]);
            hi[3] = (_Float16)v.w; lo[3] = (_Float16)(v.w - (float)hi[3]);
            // fragment offset (f16 units): q*512 + kg*256 + rl*8 + j0*4
            int off = ((k0 >> 4) << 9) + (((k0 >> 3) & 1) << 8)
                    + (rl << 3) + (((k0 >> 2) & 1) << 2);
            *(f16x4*)(S + off)        = hi;      // hi half [0, 8192)
            *(f16x4*)(S + off + 8192) = lo;      // lo half [8192, 16384)
        }
        if (tid < 32) minpair[rb * 32 + tid] = 0xFFFFFFFFFFFFFFFFull;
        __syncthreads();
        // LDS layout == output layout: straight coalesced copy (32 KB)
        float4* dst = (float4*)(Xp + (size_t)rb * 16384);
        const float4* sls = (const float4*)S;
        #pragma unroll
        for (int i = 0; i < 8; ++i) {
            int g = i * 256 + tid;
            dst[g] = sls[g];
        }
    } else {
        // ---- emb part: wave per codebook row ----
        int wave = ((bid - 512) << 2) + (tid >> 6);   // 0..8191
        int lane = tid & 63;
        int r    = wave;
        const float* src = emb + (size_t)r * DDIM;
        float4 v = ((const float4*)src)[lane];
        float s = v.x*v.x + v.y*v.y + v.z*v.z + v.w*v.w;  // ||e||^2 of original e
        #pragma unroll
        for (int m = 32; m; m >>= 1) s += __shfl_xor(s, m, 64);
        float4 t;                                         // fold the -2 in
        t.x = -2.0f * v.x; t.y = -2.0f * v.y; t.z = -2.0f * v.z; t.w = -2.0f * v.w;
        f16x4 hi, lo;
        hi[0] = (_Float16)t.x; lo[0] = (_Float16)(t.x - (float)hi[0]);
        hi[1] = (_Float16)t.y; lo[1] = (_Float16)(t.y - (float)hi[1]);
        hi[2] = (_Float16)t.z; lo[2] = (_Float16)(t.z - (float)hi[2]);
        hi[3] = (_Float16)t.w; lo[3] = (_Float16)(t.w - (float)hi[3]);
        _Float16* dst = Bp + (size_t)r * 512;
        *(f16x4*)(dst + lane * 4)       = hi;
        *(f16x4*)(dst + 256 + lane * 4) = lo;
        if (lane == 0) {
            neF[r] = s;
            counts[r] = 0;
        }
    }
}

// Barrier-free argmin GEMM, codes-as-M, mfma_f32_32x32x16_f16, 2-chunk blocked.
// R14/R20 structure: acc[2][2], unroll 2, launch_bounds(512,4), transposed
// conflict-free code slab, JIT loads. R22: + setprio around MFMA cluster.
#define MFMA16(A, B, C) __builtin_amdgcn_mfma_f32_32x32x16_f16(A, B, C, 0, 0, 0)

__global__ __launch_bounds__(512, 4) void argmin_seg(
    const _Float16* __restrict__ Xp, const _Float16* __restrict__ Bp,
    const float* __restrict__ neF, unsigned long long* __restrict__ minpair) {
    __shared__ __align__(16) _Float16 Cs[64 * 512];   // 64 KB, nothing else

    const int tid  = threadIdx.x;
    const int lane = tid & 63;
    const int w    = tid >> 6;     // 0..7
    const int c32  = lane & 31;
    const int kg   = lane >> 5;

    const int rg      = blockIdx.x & 7;
    const int seg     = blockIdx.x >> 3;
    const int rowBase = rg * 2048;
    const int code0   = seg * 64;

    // stage code slab TRANSPOSED: LDS chunk j (1 KB, linear dest) holds
    // { slot 2*(j&31)+0 : codes 0..31 | slot 2*(j&31)+1 : codes 0..31 } of
    // code-half (j>>5). Lane l fetches global Bp[code0 + (j&32) + (l&31)]
    // slot (2*(j&31) + (l>>5)).  (16B-gather src; prologue-only, L2-hot.)
    #pragma unroll
    for (int i = 0; i < 8; ++i) {
        int j    = w * 8 + i;
        int code = code0 + (j & 32) + (lane & 31);
        int s    = ((j & 31) << 1) | (lane >> 5);
        load_lds16((const char*)Bp + ((size_t)code << 10) + (s << 4),
                   (char*)Cs + (j << 10));
    }
    __syncthreads();   // the only barrier

    // read base: lane offset c32*16 within a 512B slot-row, kg picks the
    // adjacent slot. Per q: 4 reads at compile-time offsets, each wave-
    // contiguous 1 KB -> conflict-free.
    const char* cpb = (const char*)Cs + (kg << 9) + (c32 << 4);

    const int wBase = rowBase + w * 256;   // 4 chunk-pairs of 64 rows per wave
    for (int c2 = 0; c2 < 4; ++c2) {
        const int rb0 = (wBase >> 5) + c2 * 2;
        const char* xb0 = (const char*)Xp + (size_t)rb0 * 32768 + lane * 16;
        const char* xb1 = xb0 + 32768;
        f32x16 acc[2][2];   // [chunk][mt] - 4 independent MFMA chains, 64 AGPR
        #pragma unroll
        for (int i = 0; i < 16; ++i) {
            acc[0][0][i] = 0.0f; acc[0][1][i] = 0.0f;
            acc[1][0][i] = 0.0f; acc[1][1][i] = 0.0f;
        }

        #pragma unroll 2
        for (int q = 0; q < 16; ++q) {
            f16x8 xh0 = *(const f16x8*)(xb0 + q * 1024);
            f16x8 xl0 = *(const f16x8*)(xb0 + 16384 + q * 1024);
            f16x8 xh1 = *(const f16x8*)(xb1 + q * 1024);
            f16x8 xl1 = *(const f16x8*)(xb1 + 16384 + q * 1024);
            f16x8 ch0 = *(const f16x8*)(cpb + q * 1024);
            f16x8 cl0 = *(const f16x8*)(cpb + 16384 + q * 1024);
            f16x8 ch1 = *(const f16x8*)(cpb + 32768 + q * 1024);
            f16x8 cl1 = *(const f16x8*)(cpb + 49152 + q * 1024);
            // 12 MFMAs, chain-interleaved (each chain's next issue is 4 slots
            // away). T5: raise wave priority across the pure-MFMA cluster so
            // the CU scheduler favors the bursting wave over load-issuing
            // siblings (barrier-free -> waves drift -> role diversity).
            __builtin_amdgcn_s_setprio(1);
            acc[0][0] = MFMA16(ch0, xh0, acc[0][0]);
            acc[0][1] = MFMA16(ch1, xh0, acc[0][1]);
            acc[1][0] = MFMA16(ch0, xh1, acc[1][0]);
            acc[1][1] = MFMA16(ch1, xh1, acc[1][1]);
            acc[0][0] = MFMA16(ch0, xl0, acc[0][0]);
            acc[0][1] = MFMA16(ch1, xl0, acc[0][1]);
            acc[1][0] = MFMA16(ch0, xl1, acc[1][0]);
            acc[1][1] = MFMA16(ch1, xl1, acc[1][1]);
            acc[0][0] = MFMA16(cl0, xh0, acc[0][0]);
            acc[0][1] = MFMA16(cl1, xh0, acc[0][1]);
            acc[1][0] = MFMA16(cl0, xh1, acc[1][0]);
            acc[1][1] = MFMA16(cl1, xh1, acc[1][1]);
            __builtin_amdgcn_s_setprio(0);
        }

        // epilogue: ne loaded here only (L1-hot after first iter). Code id of
        // acc[ck][mt][r] = code0 + mt*32 + 4*kg + (r&3) + 8*(r>>2); (mt,r)
        // ascending <=> id ascending; strict < => first(lowest-index)-wins.
        f32x4v ne4[2][4];
        #pragma unroll
        for (int mt = 0; mt < 2; ++mt)
            #pragma unroll
            for (int g2 = 0; g2 < 4; ++g2)
                ne4[mt][g2] = *(const f32x4v*)(neF + code0 + mt * 32 + g2 * 8 + 4 * kg);
        #pragma unroll
        for (int ck = 0; ck < 2; ++ck) {
            float best = 3.402823466e+38f;
            int   bi   = 0;
            #pragma unroll
            for (int mt = 0; mt < 2; ++mt)
                #pragma unroll
                for (int r = 0; r < 16; ++r) {
                    float d  = acc[ck][mt][r] + ne4[mt][r >> 2][r & 3];
                    int   id = code0 + mt * 32 + 4 * kg + ((r & 3) + 8 * (r >> 2));
                    if (d < best) { best = d; bi = id; }
                }
            float ov = __shfl_xor(best, 32, 64);
            int   oi = __shfl_xor(bi, 32, 64);
            if (ov < best || (ov == best && oi < bi)) { best = ov; bi = oi; }
            if (kg == 0) {
                int row = (rb0 + ck) * 32 + c32;
                unsigned u = __float_as_uint(best);
                u = (u & 0x80000000u) ? ~u : (u | 0x80000000u);   // total-order map
                atomicMin(&minpair[row],
                          (((unsigned long long)u) << 32) | (unsigned)bi);
            }
        }
    }
}

// decode packed min, gather codebook row, write quantized_sg + float index,
// histogram atomic + per-block SSE partials.
__global__ __launch_bounds__(256) void finalize_kernel(
    const float* __restrict__ x, const float* __restrict__ emb,
    const unsigned long long* __restrict__ minpair,
    float* __restrict__ out_q, float* __restrict__ out_idx,
    int* __restrict__ counts, float* __restrict__ parts) {
    __shared__ float rde[4], rdq[4];
    int wv   = threadIdx.x >> 6;
    int row  = (blockIdx.x << 2) + wv;
    int lane = threadIdx.x & 63;

    int bi = (int)(minpair[row] & 0xFFFFFFFFull);

    float4 xv = ((const float4*)(x   + (size_t)row * DDIM))[lane];
    float4 ev = ((const float4*)(emb + (size_t)bi  * DDIM))[lane];
    float4 q;
    q.x = xv.x + (ev.x - xv.x);
    q.y = xv.y + (ev.y - xv.y);
    q.z = xv.z + (ev.z - xv.z);
    q.w = xv.w + (ev.w - xv.w);
    ((float4*)(out_q + (size_t)row * DDIM))[lane] = q;

    float de = (ev.x - xv.x) * (ev.x - xv.x) + (ev.y - xv.y) * (ev.y - xv.y)
             + (ev.z - xv.z) * (ev.z - xv.z) + (ev.w - xv.w) * (ev.w - xv.w);
    float dq = (q.x - ev.x) * (q.x - ev.x) + (q.y - ev.y) * (q.y - ev.y)
             + (q.z - ev.z) * (q.z - ev.z) + (q.w - ev.w) * (q.w - ev.w);
    #pragma unroll
    for (int m = 32; m; m >>= 1) {
        de += __shfl_xor(de, m, 64);
        dq += __shfl_xor(dq, m, 64);
    }
    if (lane == 0) {
        out_idx[row] = (float)bi;
        atomicAdd(&counts[bi], 1);
        rde[wv] = de; rdq[wv] = dq;
    }
    __syncthreads();
    if (threadIdx.x == 0) {
        parts[blockIdx.x]        = rde[0] + rde[1] + rde[2] + rde[3];
        parts[4096 + blockIdx.x] = rdq[0] + rdq[1] + rdq[2] + rdq[3];
    }
}

__global__ __launch_bounds__(256) void scalars_kernel(
    const int* __restrict__ counts, const float* __restrict__ parts,
    float* __restrict__ out_loss, float* __restrict__ out_perp) {
    __shared__ float red[256], rde[256], rdq[256];
    float local = 0.0f, de = 0.0f, dq = 0.0f;
    for (int k = threadIdx.x; k < KCODES; k += 256) {
        float p = (float)counts[k] * (1.0f / (float)ND_ROWS);
        local += p * logf(p + 1e-10f);
    }
    for (int k = threadIdx.x; k < 4096; k += 256) {
        de += parts[k];
        dq += parts[4096 + k];
    }
    red[threadIdx.x] = local; rde[threadIdx.x] = de; rdq[threadIdx.x] = dq;
    __syncthreads();
    for (int s = 128; s; s >>= 1) {
        if (threadIdx.x < s) {
            red[threadIdx.x] += red[threadIdx.x + s];
            rde[threadIdx.x] += rde[threadIdx.x + s];
            rdq[threadIdx.x] += rdq[threadIdx.x + s];
        }
        __syncthreads();
    }
    if (threadIdx.x == 0) {
        *out_perp = expf(-red[0]);
        float invn = 1.0f / (float)(ND_ROWS * DDIM);
        *out_loss = rdq[0] * invn + 0.25f * (rde[0] * invn);
    }
}

extern "C" void kernel_launch(void* const* d_in, const int* in_sizes, int n_in,
                              void* d_out, int out_size, void* d_ws, size_t ws_size,
                              hipStream_t stream) {
    const float* x   = (const float*)d_in[0];
    const float* emb = (const float*)d_in[1];

    char* ws = (char*)d_ws;
    unsigned long long* minpair = (unsigned long long*)ws;         // 128 KB
    int*      counts = (int*)(ws + 131072);                        // 32 KB
    float*    parts  = (float*)(ws + 163840);                      // 32 KB
    float*    neF    = (float*)(ws + 196608);                      // 32 KB
    _Float16* Xp     = (_Float16*)(ws + 229376);                   // 16.8 MB
    _Float16* Bp     = (_Float16*)(ws + 17006592);                 // 8.4 MB

    float* out_q    = (float*)d_out;
    float* out_idx  = out_q + (size_t)ND_ROWS * DDIM;
    float* out_loss = out_idx + ND_ROWS;
    float* out_perp = out_loss + 1;

    prep_kernel<<<512 + KCODES / 4, 256, 0, stream>>>(x, emb, Xp, Bp, neF,
                                                      minpair, counts);
    argmin_seg<<<NRG * NSEG, 512, 0, stream>>>(Xp, Bp, neF, minpair);
    finalize_kernel<<<ND_ROWS / 4, 256, 0, stream>>>(x, emb, minpair,
                                                     out_q, out_idx, counts, parts);
    scalars_kernel<<<1, 256, 0, stream>>>(counts, parts, out_loss, out_perp);
}

// Round 13
// 300.223 us; speedup vs baseline: 1.3918x; 1.0057x over previous
//
#include <hip/hip_runtime.h>
#include <math.h>
#include <stdint.h>

#define ND_ROWS 16384
#define DDIM    256
#define KCODES  8192
#define NSEG    128        // 64-code segments
#define NRG     8          // row groups (XCD-affine), 2048 rows each

typedef _Float16 f16x4 __attribute__((ext_vector_type(4)));
typedef _Float16 f16x8 __attribute__((ext_vector_type(8)));
typedef float    f32x4v __attribute__((ext_vector_type(4)));
typedef float    f32x16 __attribute__((ext_vector_type(16)));

// R23: the untested matrix cell - WIDE row tile + pure JIT loads.
// {tile x staging} record: (2chunk,JIT)=213us, (2chunk,pipe)=225, (wide,pipe)
// = spill (R12/R16: pipeline regs + wide acc > 256 cap). Wide+JIT never
// measured. acc[4][2] (128 rows/wave-pass, 24-MFMA clusters): liveness
// ~128 AGPR + ~60 V ~= 190 -> no spill (V cap 128 at the 2-wave tier).
// Tests the duty-conservation law (4w x 11% = 2w x 22% = 44%): per-q-step
// shared cost? Doubling MFMAs/q-step halves q-steps at constant MFMA work;
// loads/MFMA 0.67 -> 0.5; chain-reissue gap 128 -> 256 cyc (dep-latency
// probe). Pre-commit: neutral (~215-225) => conservation is structural,
// revert to best next round and stop.
// ---------------------------------------------------------------------------
// ws layout (bytes):
//   minpair [0,        131072)   u64[16384]  (init by prep)
//   counts  [131072,   163840)   int[8192]   (init by prep)
//   parts   [163840,   196608)   de[4096] | dq[4096]
//   neF     [196608,   229376)   float[8192] = ||e||^2
//   Xp      [229376,   17006592) x as MFMA B-operand fragments, 16.8 MB:
//            per 32-row block rb (32 KB): hi q=0..15 then lo q=0..15; unit
//            (rb,q) = 1 KB; 16B chunk index within unit = (kg<<5)|rl holding
//            halves k = q*16 + kg*8 .. +8 of row rl.
//   Bp      [17006592, 25395200) 8192 x 512 f16 = [-2e_hi(256) | -2e_lo(256)]
// ---------------------------------------------------------------------------

__device__ __attribute__((always_inline)) inline void load_lds16(const void* g, void* l) {
    __builtin_amdgcn_global_load_lds((const __attribute__((address_space(1))) void*)g,
                                     (__attribute__((address_space(3))) void*)l, 16, 0, 0);
}

// Blocks 0..511: x-transpose blocks (one rb = 32 rows each; LDS-staged,
// coalesced global I/O). Blocks 512..2559: emb wave-per-row.
__global__ __launch_bounds__(256) void prep_kernel(const float* __restrict__ x,
                                                   const float* __restrict__ emb,
                                                   _Float16* __restrict__ Xp,
                                                   _Float16* __restrict__ Bp,
                                                   float* __restrict__ neF,
                                                   unsigned long long* __restrict__ minpair,
                                                   int* __restrict__ counts) {
    __shared__ __align__(16) _Float16 S[16384];   // 32 KB staging (x-blocks)
    const int bid = blockIdx.x;
    const int tid = threadIdx.x;

    if (bid < 512) {
        // ---- x part: rb = bid, rows rb*32 .. +32 ----
        const int rb = bid;
        const float4* src = (const float4*)(x + (size_t)rb * 32 * DDIM); // 2048 float4
        #pragma unroll
        for (int i = 0; i < 8; ++i) {
            int g = i * 256 + tid;           // float4 index within the rb block
            float4 v = src[g];
            int rl = g >> 6;                 // row 0..31
            int k0 = (g & 63) << 2;          // k = k0 .. k0+3
            f16x4 hi, lo;
            hi[0] = (_Float16)v.x; lo[0] = (_Float16)(v.x - (float)hi[0]);
            hi[1] = (_Float16)v.y; lo[1] = (_Float16)(v.y - (float)hi[1]);
            hi[2] = (_Float16)v.z; lo[2] = (_Float16)(v.z - (float)hi[2]);
            hi[3] = (_Float16)v.w; lo[3] = (_Float16)(v.w - (float)hi[3]);
            // fragment offset (f16 units): q*512 + kg*256 + rl*8 + j0*4
            int off = ((k0 >> 4) << 9) + (((k0 >> 3) & 1) << 8)
                    + (rl << 3) + (((k0 >> 2) & 1) << 2);
            *(f16x4*)(S + off)        = hi;      // hi half [0, 8192)
            *(f16x4*)(S + off + 8192) = lo;      // lo half [8192, 16384)
        }
        if (tid < 32) minpair[rb * 32 + tid] = 0xFFFFFFFFFFFFFFFFull;
        __syncthreads();
        // LDS layout == output layout: straight coalesced copy (32 KB)
        float4* dst = (float4*)(Xp + (size_t)rb * 16384);
        const float4* sls = (const float4*)S;
        #pragma unroll
        for (int i = 0; i < 8; ++i) {
            int g = i * 256 + tid;
            dst[g] = sls[g];
        }
    } else {
        // ---- emb part: wave per codebook row ----
        int wave = ((bid - 512) << 2) + (tid >> 6);   // 0..8191
        int lane = tid & 63;
        int r    = wave;
        const float* src = emb + (size_t)r * DDIM;
        float4 v = ((const float4*)src)[lane];
        float s = v.x*v.x + v.y*v.y + v.z*v.z + v.w*v.w;  // ||e||^2 of original e
        #pragma unroll
        for (int m = 32; m; m >>= 1) s += __shfl_xor(s, m, 64);
        float4 t;                                         // fold the -2 in
        t.x = -2.0f * v.x; t.y = -2.0f * v.y; t.z = -2.0f * v.z; t.w = -2.0f * v.w;
        f16x4 hi, lo;
        hi[0] = (_Float16)t.x; lo[0] = (_Float16)(t.x - (float)hi[0]);
        hi[1] = (_Float16)t.y; lo[1] = (_Float16)(t.y - (float)hi[1]);
        hi[2] = (_Float16)t.z; lo[2] = (_Float16)(t.z - (float)hi[2]);
        hi[3] = (_Float16)t.w; lo[3] = (_Float16)(t.w - (float)hi[3]);
        _Float16* dst = Bp + (size_t)r * 512;
        *(f16x4*)(dst + lane * 4)       = hi;
        *(f16x4*)(dst + 256 + lane * 4) = lo;
        if (lane == 0) {
            neF[r] = s;
            counts[r] = 0;
        }
    }
}

// Barrier-free argmin GEMM, codes-as-M, mfma_f32_32x32x16_f16.
// R23: 4-chunk (128-row) JIT tile, acc[4][2] = 8 chains (128 AGPR),
// transposed conflict-free slab, launch_bounds(512,2). 24-MFMA clusters,
// chain-reissue gap 8 slots (256 cyc). setprio kept (as in R22).
#define MFMA16(A, B, C) __builtin_amdgcn_mfma_f32_32x32x16_f16(A, B, C, 0, 0, 0)

__global__ __launch_bounds__(512, 2) void argmin_seg(
    const _Float16* __restrict__ Xp, const _Float16* __restrict__ Bp,
    const float* __restrict__ neF, unsigned long long* __restrict__ minpair) {
    __shared__ __align__(16) _Float16 Cs[64 * 512];   // 64 KB, nothing else

    const int tid  = threadIdx.x;
    const int lane = tid & 63;
    const int w    = tid >> 6;     // 0..7
    const int c32  = lane & 31;
    const int kg   = lane >> 5;

    const int rg      = blockIdx.x & 7;
    const int seg     = blockIdx.x >> 3;
    const int rowBase = rg * 2048;
    const int code0   = seg * 64;

    // stage code slab TRANSPOSED: LDS chunk j (1 KB, linear dest) holds
    // { slot 2*(j&31)+0 : codes 0..31 | slot 2*(j&31)+1 : codes 0..31 } of
    // code-half (j>>5). Lane l fetches global Bp[code0 + (j&32) + (l&31)]
    // slot (2*(j&31) + (l>>5)).  (16B-gather src; prologue-only, L2-hot.)
    #pragma unroll
    for (int i = 0; i < 8; ++i) {
        int j    = w * 8 + i;
        int code = code0 + (j & 32) + (lane & 31);
        int s    = ((j & 31) << 1) | (lane >> 5);
        load_lds16((const char*)Bp + ((size_t)code << 10) + (s << 4),
                   (char*)Cs + (j << 10));
    }
    __syncthreads();   // the only barrier

    // read base: lane offset c32*16 within a 512B slot-row, kg picks the
    // adjacent slot. Per q: 4 reads at compile-time offsets, each wave-
    // contiguous 1 KB -> conflict-free.
    const char* cpb = (const char*)Cs + (kg << 9) + (c32 << 4);

    const int wBase = rowBase + w * 256;   // 2 groups of 128 rows per wave
    #pragma unroll 1
    for (int c2 = 0; c2 < 2; ++c2) {
        const int rb0 = (wBase >> 5) + c2 * 4;
        const char* xb = (const char*)Xp + (size_t)rb0 * 32768 + lane * 16;
        f32x16 acc[4][2];   // [chunk][mt] - 8 independent MFMA chains, 128 AGPR
        #pragma unroll
        for (int ck = 0; ck < 4; ++ck)
            #pragma unroll
            for (int i = 0; i < 16; ++i) { acc[ck][0][i] = 0.0f; acc[ck][1][i] = 0.0f; }

        #pragma unroll 2
        for (int q = 0; q < 16; ++q) {
            f16x8 xh0 = *(const f16x8*)(xb + q * 1024);
            f16x8 xl0 = *(const f16x8*)(xb + 16384 + q * 1024);
            f16x8 xh1 = *(const f16x8*)(xb + 32768 + q * 1024);
            f16x8 xl1 = *(const f16x8*)(xb + 49152 + q * 1024);
            f16x8 xh2 = *(const f16x8*)(xb + 65536 + q * 1024);
            f16x8 xl2 = *(const f16x8*)(xb + 81920 + q * 1024);
            f16x8 xh3 = *(const f16x8*)(xb + 98304 + q * 1024);
            f16x8 xl3 = *(const f16x8*)(xb + 114688 + q * 1024);
            f16x8 ch0 = *(const f16x8*)(cpb + q * 1024);
            f16x8 cl0 = *(const f16x8*)(cpb + 16384 + q * 1024);
            f16x8 ch1 = *(const f16x8*)(cpb + 32768 + q * 1024);
            f16x8 cl1 = *(const f16x8*)(cpb + 49152 + q * 1024);
            // 24 MFMAs in 3 term-groups of 8; chain (ck,mt) reissues 8 slots
            // (256 cyc) apart. Products: ch*xh + ch*xl + cl*xh.
            __builtin_amdgcn_s_setprio(1);
            acc[0][0] = MFMA16(ch0, xh0, acc[0][0]);
            acc[0][1] = MFMA16(ch1, xh0, acc[0][1]);
            acc[1][0] = MFMA16(ch0, xh1, acc[1][0]);
            acc[1][1] = MFMA16(ch1, xh1, acc[1][1]);
            acc[2][0] = MFMA16(ch0, xh2, acc[2][0]);
            acc[2][1] = MFMA16(ch1, xh2, acc[2][1]);
            acc[3][0] = MFMA16(ch0, xh3, acc[3][0]);
            acc[3][1] = MFMA16(ch1, xh3, acc[3][1]);
            acc[0][0] = MFMA16(ch0, xl0, acc[0][0]);
            acc[0][1] = MFMA16(ch1, xl0, acc[0][1]);
            acc[1][0] = MFMA16(ch0, xl1, acc[1][0]);
            acc[1][1] = MFMA16(ch1, xl1, acc[1][1]);
            acc[2][0] = MFMA16(ch0, xl2, acc[2][0]);
            acc[2][1] = MFMA16(ch1, xl2, acc[2][1]);
            acc[3][0] = MFMA16(ch0, xl3, acc[3][0]);
            acc[3][1] = MFMA16(ch1, xl3, acc[3][1]);
            acc[0][0] = MFMA16(cl0, xh0, acc[0][0]);
            acc[0][1] = MFMA16(cl1, xh0, acc[0][1]);
            acc[1][0] = MFMA16(cl0, xh1, acc[1][0]);
            acc[1][1] = MFMA16(cl1, xh1, acc[1][1]);
            acc[2][0] = MFMA16(cl0, xh2, acc[2][0]);
            acc[2][1] = MFMA16(cl1, xh2, acc[2][1]);
            acc[3][0] = MFMA16(cl0, xh3, acc[3][0]);
            acc[3][1] = MFMA16(cl1, xh3, acc[3][1]);
            __builtin_amdgcn_s_setprio(0);
        }

        // epilogue: ne loaded here only (L1-hot after first iter). Code id of
        // acc[ck][mt][r] = code0 + mt*32 + 4*kg + (r&3) + 8*(r>>2); (mt,r)
        // ascending <=> id ascending; strict < => first(lowest-index)-wins.
        f32x4v ne4[2][4];
        #pragma unroll
        for (int mt = 0; mt < 2; ++mt)
            #pragma unroll
            for (int g2 = 0; g2 < 4; ++g2)
                ne4[mt][g2] = *(const f32x4v*)(neF + code0 + mt * 32 + g2 * 8 + 4 * kg);
        #pragma unroll
        for (int ck = 0; ck < 4; ++ck) {
            float best = 3.402823466e+38f;
            int   bi   = 0;
            #pragma unroll
            for (int mt = 0; mt < 2; ++mt)
                #pragma unroll
                for (int r = 0; r < 16; ++r) {
                    float d  = acc[ck][mt][r] + ne4[mt][r >> 2][r & 3];
                    int   id = code0 + mt * 32 + 4 * kg + ((r & 3) + 8 * (r >> 2));
                    if (d < best) { best = d; bi = id; }
                }
            float ov = __shfl_xor(best, 32, 64);
            int   oi = __shfl_xor(bi, 32, 64);
            if (ov < best || (ov == best && oi < bi)) { best = ov; bi = oi; }
            if (kg == 0) {
                int row = (rb0 + ck) * 32 + c32;
                unsigned u = __float_as_uint(best);
                u = (u & 0x80000000u) ? ~u : (u | 0x80000000u);   // total-order map
                atomicMin(&minpair[row],
                          (((unsigned long long)u) << 32) | (unsigned)bi);
            }
        }
    }
}

// decode packed min, gather codebook row, write quantized_sg + float index,
// histogram atomic + per-block SSE partials.
__global__ __launch_bounds__(256) void finalize_kernel(
    const float* __restrict__ x, const float* __restrict__ emb,
    const unsigned long long* __restrict__ minpair,
    float* __restrict__ out_q, float* __restrict__ out_idx,
    int* __restrict__ counts, float* __restrict__ parts) {
    __shared__ float rde[4], rdq[4];
    int wv   = threadIdx.x >> 6;
    int row  = (blockIdx.x << 2) + wv;
    int lane = threadIdx.x & 63;

    int bi = (int)(minpair[row] & 0xFFFFFFFFull);

    float4 xv = ((const float4*)(x   + (size_t)row * DDIM))[lane];
    float4 ev = ((const float4*)(emb + (size_t)bi  * DDIM))[lane];
    float4 q;
    q.x = xv.x + (ev.x - xv.x);
    q.y = xv.y + (ev.y - xv.y);
    q.z = xv.z + (ev.z - xv.z);
    q.w = xv.w + (ev.w - xv.w);
    ((float4*)(out_q + (size_t)row * DDIM))[lane] = q;

    float de = (ev.x - xv.x) * (ev.x - xv.x) + (ev.y - xv.y) * (ev.y - xv.y)
             + (ev.z - xv.z) * (ev.z - xv.z) + (ev.w - xv.w) * (ev.w - xv.w);
    float dq = (q.x - ev.x) * (q.x - ev.x) + (q.y - ev.y) * (q.y - ev.y)
             + (q.z - ev.z) * (q.z - ev.z) + (q.w - ev.w) * (q.w - ev.w);
    #pragma unroll
    for (int m = 32; m; m >>= 1) {
        de += __shfl_xor(de, m, 64);
        dq += __shfl_xor(dq, m, 64);
    }
    if (lane == 0) {
        out_idx[row] = (float)bi;
        atomicAdd(&counts[bi], 1);
        rde[wv] = de; rdq[wv] = dq;
    }
    __syncthreads();
    if (threadIdx.x == 0) {
        parts[blockIdx.x]        = rde[0] + rde[1] + rde[2] + rde[3];
        parts[4096 + blockIdx.x] = rdq[0] + rdq[1] + rdq[2] + rdq[3];
    }
}

__global__ __launch_bounds__(256) void scalars_kernel(
    const int* __restrict__ counts, const float* __restrict__ parts,
    float* __restrict__ out_loss, float* __restrict__ out_perp) {
    __shared__ float red[256], rde[256], rdq[256];
    float local = 0.0f, de = 0.0f, dq = 0.0f;
    for (int k = threadIdx.x; k < KCODES; k += 256) {
        float p = (float)counts[k] * (1.0f / (float)ND_ROWS);
        local += p * logf(p + 1e-10f);
    }
    for (int k = threadIdx.x; k < 4096; k += 256) {
        de += parts[k];
        dq += parts[4096 + k];
    }
    red[threadIdx.x] = local; rde[threadIdx.x] = de; rdq[threadIdx.x] = dq;
    __syncthreads();
    for (int s = 128; s; s >>= 1) {
        if (threadIdx.x < s) {
            red[threadIdx.x] += red[threadIdx.x + s];
            rde[threadIdx.x] += rde[threadIdx.x + s];
            rdq[threadIdx.x] += rdq[threadIdx.x + s];
        }
        __syncthreads();
    }
    if (threadIdx.x == 0) {
        *out_perp = expf(-red[0]);
        float invn = 1.0f / (float)(ND_ROWS * DDIM);
        *out_loss = rdq[0] * invn + 0.25f * (rde[0] * invn);
    }
}

extern "C" void kernel_launch(void* const* d_in, const int* in_sizes, int n_in,
                              void* d_out, int out_size, void* d_ws, size_t ws_size,
                              hipStream_t stream) {
    const float* x   = (const float*)d_in[0];
    const float* emb = (const float*)d_in[1];

    char* ws = (char*)d_ws;
    unsigned long long* minpair = (unsigned long long*)ws;         // 128 KB
    int*      counts = (int*)(ws + 131072);                        // 32 KB
    float*    parts  = (float*)(ws + 163840);                      // 32 KB
    float*    neF    = (float*)(ws + 196608);                      // 32 KB
    _Float16* Xp     = (_Float16*)(ws + 229376);                   // 16.8 MB
    _Float16* Bp     = (_Float16*)(ws + 17006592);                 // 8.4 MB

    float* out_q    = (float*)d_out;
    float* out_idx  = out_q + (size_t)ND_ROWS * DDIM;
    float* out_loss = out_idx + ND_ROWS;
    float* out_perp = out_loss + 1;

    prep_kernel<<<512 + KCODES / 4, 256, 0, stream>>>(x, emb, Xp, Bp, neF,
                                                      minpair, counts);
    argmin_seg<<<NRG * NSEG, 512, 0, stream>>>(Xp, Bp, neF, minpair);
    finalize_kernel<<<ND_ROWS / 4, 256, 0, stream>>>(x, emb, minpair,
                                                     out_q, out_idx, counts, parts);
    scalars_kernel<<<1, 256, 0, stream>>>(counts, parts, out_loss, out_perp);
}